// Round 11
// baseline (150.158 us; speedup 1.0000x reference)
//
#include <hip/hip_runtime.h>
#include <hip/hip_bf16.h>

typedef __attribute__((ext_vector_type(8))) short bf16x8;
typedef __attribute__((ext_vector_type(4))) float f32x4;
typedef __attribute__((ext_vector_type(4))) short s16x4;
typedef __attribute__((ext_vector_type(4))) float f32v4;
typedef unsigned short u16;

__device__ inline u16 f2b(float f){ __hip_bfloat16 b = __float2bfloat16(f); return __builtin_bit_cast(unsigned short, b); }
__device__ inline float b2f(u16 u){ unsigned int x = ((unsigned int)u)<<16; return __builtin_bit_cast(float, x); }
__device__ inline float sigm(float x){ return 1.f/(1.f+__expf(-x)); }
__device__ inline float tanhfast(float x){ float e = __expf(2.f*x); return 1.f - 2.f/(e+1.f); }

__device__ inline f32x4 mfma16(bf16x8 a, bf16x8 b, f32x4 c){
  return __builtin_amdgcn_mfma_f32_16x16x32_bf16(a, b, c, 0, 0, 0);
}

// in2T fragment-tiled (R9-verified): element (row, col) at
//   ((row>>4)*8 + (col>>5))*512 + (((col>>3)&3)*16 + (row&15))*8 + (col&7)
// -> a 16x16x32 A-frag (row-tile rt, k-tile kk) is 512 u16, read at lane*8.
__device__ __forceinline__ void in2t_store(u16* t, int row, int col, u16 v){
  int rt = row>>4, kk = col>>5, khi = (col>>3)&3, e = col&7;
  t[(size_t)(rt*8+kk)*512 + (khi*16 + (row&15))*8 + e] = v;
}
__device__ __forceinline__ s16x4 in2t_load4(const u16* t, int row, int col){
  int rt = row>>4, kk = col>>5, khi = (col>>3)&3, e = col&7;   // col 4-aligned
  return *(const s16x4*)(t + (size_t)(rt*8+kk)*512 + (khi*16 + (row&15))*8 + e);
}

// ---------------- weight conversion ----------------
struct CVA {
  const float *w2a, *w2b, *wihQ, *whhQ, *wihSg, *whhSg, *wihS, *whhS, *wfc3, *wfc4;
  u16 *waB, *wbB, *wihQp, *whhQb, *wihSgB, *whhSgB, *wihSp, *whhSb, *wfc3p, *wfc4p;
};

// waB tiled (R9-verified): [t=640][kk=8][lane=64][e=8];
//   (t,kk,l,e) = W2a[t*16+(l&15)][kk*32+(l>>4)*8+e]
// wbB tiled: [s=320][lane=64][e=8]; (s,l,e) = W2b[(l&15)][s*32+(l>>4)*8+e] (o>=8 -> 0)
__global__ __launch_bounds__(256) void kconv(CVA a){
  int id = blockIdx.x*256 + threadIdx.x;
  if (id < 2621440){
    int t  = id >> 12;
    int r  = id & 4095;
    int kk = r >> 9;
    int l  = (r >> 3) & 63;
    int e  = id & 7;
    int col = t*16 + (l & 15);
    int k   = kk*32 + (l >> 4)*8 + e;
    a.waB[id] = f2b(a.w2a[col*256 + k]);
    return;
  }
  id -= 2621440;
  if (id < 163840){
    int s = id >> 9;
    int r = id & 511;
    int l = r >> 3;
    int e = r & 7;
    int o = l & 15;
    int k = s*32 + (l >> 4)*8 + e;
    a.wbB[id] = (o < 8) ? f2b(a.w2b[o*10240 + k]) : (u16)0;
    return;
  }
  id -= 163840;
  if (id < 12288){ int j=id>>5, k=id&31; a.wihQp[id] = (k<20)? f2b(a.wihQ[j*20+k]) : (u16)0; return; }
  id -= 12288;
  if (id < 49152){ a.whhQb[id] = f2b(a.whhQ[id]); return; }
  id -= 49152;
  if (id < 49152){ a.wihSgB[id] = f2b(a.wihSg[id]); return; }
  id -= 49152;
  if (id < 49152){ a.whhSgB[id] = f2b(a.whhSg[id]); return; }
  id -= 49152;
  if (id < 12288){ int j=id>>5, k=id&31; a.wihSp[id] = (k<6)? f2b(a.wihS[j*6+k]) : (u16)0; return; }
  id -= 12288;
  if (id < 49152){ a.whhSb[id] = f2b(a.whhS[id]); return; }
  id -= 49152;
  if (id < 2560){ int j=id/160, k=id%160; a.wfc3p[id] = (k<136)? f2b(a.wfc3[j*136+k]) : (u16)0; return; }
}

__global__ __launch_bounds__(256) void kconv_fc4(const float* wfc4, u16* wfc4p){
  int id = blockIdx.x*256 + threadIdx.x;
  if (id < 20480){ int j=id/160, k=id%160; wfc4p[id] = (k<144)? f2b(wfc4[j*144+k]) : (u16)0; }
}

// ---------------- GRU block step (32 rows, 256 threads = 4 waves) ----------------
template<int KX, int LDX, bool SOUT, bool GB16, bool GF32>
__device__ __forceinline__ void gru_step(
    const u16* sX, const u16* sH,
    const u16* __restrict__ Wih, const int ldwih, const u16* __restrict__ Whh,
    const float* __restrict__ bih, const float* __restrict__ bhh,
    float* __restrict__ gOutF, u16* sOut,
    u16* __restrict__ in2T, int row0, int colOff)
{
  const int tid = threadIdx.x;
  const int w = tid>>6, lane = tid&63, c = lane&15, khi = lane>>4;
  for (int nn=0; nn<2; ++nn){
    const int n = w*2+nn;
    const int j = n*16 + c;
    const float bir=bih[j], biz=bih[128+j], bin=bih[256+j];
    const float bhr=bhh[j], bhz=bhh[128+j], bhn=bhh[256+j];
    bf16x8 BX0[KX], BX1[KX], BX2[KX], BH0[4], BH1[4], BH2[4];
    #pragma unroll
    for (int kk=0;kk<KX;++kk){
      const u16* p = Wih + j*ldwih + kk*32 + khi*8;
      BX0[kk] = *(const bf16x8*)(p);
      BX1[kk] = *(const bf16x8*)(p + 128*ldwih);
      BX2[kk] = *(const bf16x8*)(p + 256*ldwih);
    }
    #pragma unroll
    for (int kk=0;kk<4;++kk){
      const u16* p = Whh + j*128 + kk*32 + khi*8;
      BH0[kk] = *(const bf16x8*)(p);
      BH1[kk] = *(const bf16x8*)(p + 128*128);
      BH2[kk] = *(const bf16x8*)(p + 256*128);
    }
    #pragma unroll
    for (int m=0;m<2;++m){
      f32x4 ir={0,0,0,0}, iz={0,0,0,0}, inx={0,0,0,0};
      f32x4 hr={0,0,0,0}, hz={0,0,0,0}, hn={0,0,0,0};
      #pragma unroll
      for (int kk=0;kk<KX;++kk){
        bf16x8 A = *(const bf16x8*)(sX + (m*16+c)*LDX + kk*32 + khi*8);
        ir  = mfma16(A, BX0[kk], ir);
        iz  = mfma16(A, BX1[kk], iz);
        inx = mfma16(A, BX2[kk], inx);
      }
      #pragma unroll
      for (int kk=0;kk<4;++kk){
        bf16x8 A = *(const bf16x8*)(sH + (m*16+c)*136 + kk*32 + khi*8);
        hr = mfma16(A, BH0[kk], hr);
        hz = mfma16(A, BH1[kk], hz);
        hn = mfma16(A, BH2[kk], hn);
      }
      #pragma unroll
      for (int e=0;e<4;++e){
        int r = m*16 + khi*4 + e;
        float rg = sigm(ir[e]+hr[e]+bir+bhr);
        float zg = sigm(iz[e]+hz[e]+biz+bhz);
        float ng = tanhfast(inx[e]+bin + rg*(hn[e]+bhn));
        float hold = b2f(sH[r*136 + j]);
        float hv = (1.f-zg)*ng + zg*hold;
        if (GF32) gOutF[r*128 + j] = hv;
        if (SOUT) sOut[r*136 + j] = f2b(hv);
        if (GB16) in2t_store(in2T, row0 + r, colOff + j, f2b(hv));
      }
    }
  }
}

// ---------------- K1: chain up to in2T ----------------
struct K1A {
  const float *y,*u,*m1x,*hQ,*hSg,*hS,*F,*G,*Hm,*W5,*b5,
              *bihQ,*bhhQ,*bihSg,*bhhSg,*W1,*b1,*W7,*b7,*bihS,*bhhS;
  const u16 *wihQp,*whhQ,*wihSg,*whhSg,*wihSp,*whhS;
  float *outHQ,*outHS,*xp,*dy;
  u16 *in2T;
};

__device__ __forceinline__ void load_h_tile(u16* dst, const float* src, int row0){
  const int tid = threadIdx.x;
  #pragma unroll
  for (int i=0;i<4;++i){
    int f4 = tid + i*256;
    int r = f4>>5, c4 = f4&31;
    f32v4 v = *(const f32v4*)(src + (row0+r)*128 + c4*4);
    s16x4 o;
    o[0]=(short)f2b(v[0]); o[1]=(short)f2b(v[1]);
    o[2]=(short)f2b(v[2]); o[3]=(short)f2b(v[3]);
    *(s16x4*)(dst + r*136 + c4*4) = o;
  }
}

__global__ __launch_bounds__(256) void k1(K1A a){
  __shared__ u16 sX[32*40];
  __shared__ u16 sH[32*136];
  __shared__ u16 sXL[32*136];
  __shared__ u16 sSig[32*136];
  __shared__ float sDY[64];
  const int row0 = blockIdx.x*32;
  const int tid = threadIdx.x;

  load_h_tile(sH, a.hQ, row0);
  if (tid < 32){
    int r = tid, row = row0 + r;
    float xpost[4], uu[2], xpr[4];
    #pragma unroll
    for (int i=0;i<4;++i) xpost[i]=a.m1x[row*4+i];
    uu[0]=a.u[row*2]; uu[1]=a.u[row*2+1];
    #pragma unroll
    for (int i=0;i<4;++i){
      float s=0.f;
      #pragma unroll
      for (int jj=0;jj<4;++jj) s += a.F[i*4+jj]*xpost[jj];
      #pragma unroll
      for (int jj=0;jj<2;++jj) s += a.G[i*2+jj]*uu[jj];
      xpr[i]=s; a.xp[row*4+i]=s;
    }
    #pragma unroll
    for (int nn2=0;nn2<2;++nn2){
      float s=0.f;
      #pragma unroll
      for (int jj=0;jj<4;++jj) s += a.Hm[nn2*4+jj]*xpr[jj];
      float d = a.y[row*2+nn2]-s;
      a.dy[row*2+nn2]=d; sDY[r*2+nn2]=d;
    }
    #pragma unroll
    for (int o=0;o<20;++o){
      float s=a.b5[o];
      #pragma unroll
      for (int k=0;k<4;++k) s += a.W5[o*4+k]*xpr[k];
      sX[r*40+o]=f2b(fmaxf(s,0.f));
    }
    for (int o=20;o<40;++o) sX[r*40+o]=0;
  }
  __syncthreads();
  gru_step<1,40,true,false,true>(sX, sH, a.wihQp, 32, a.whhQ, a.bihQ, a.bhhQ,
                                 a.outHQ + row0*128, sXL, nullptr, 0, 0);
  __syncthreads();
  load_h_tile(sH, a.hSg, row0);
  __syncthreads();
  gru_step<4,136,true,true,false>(sXL, sH, a.wihSg, 128, a.whhSg, a.bihSg, a.bhhSg,
                                  nullptr, sSig, a.in2T, row0, 0);
  __syncthreads();
  if (tid < 128){
    int r = tid>>2, o = tid&3;
    float s = a.b1[o];
    for (int k=0;k<128;++k) s += a.W1[o*128+k]*b2f(sSig[r*136+k]);
    sX[r*40+o] = f2b(fmaxf(s,0.f));
  } else if (tid < 192){
    int t = tid-128; int r=t>>1, o=t&1;
    float s = a.b7[o] + a.W7[o*2]*sDY[r*2] + a.W7[o*2+1]*sDY[r*2+1];
    sX[r*40+4+o] = f2b(fmaxf(s,0.f));
  }
  for (int i=tid;i<32*26;i+=256){ int r=i/26, cc=6+(i%26); sX[r*40+cc]=0; }
  load_h_tile(sH, a.hS, row0);
  __syncthreads();
  gru_step<1,40,false,true,true>(sX, sH, a.wihSp, 32, a.whhS, a.bihS, a.bhhS,
                                 a.outHS + row0*128, nullptr, a.in2T, row0, 128);
}

// ---------------- K2: fused fc2a -> relu -> fc2b, A-in-registers ----------------
// grid 256 = 32 rg x 8 ch (1 block/CU). Block: 512 thr = 8 waves, rows rg*256..+255,
// each wave OWNS 32 rows: A-frags (Af[2][8], 64 VGPR) loaded once from in2T and
// held across the whole kernel. All 8 waves sweep the SAME 40 col-steps of the
// chunk's 1280 cols -> B loads are identical addresses across waves (1 L2 fill +
// 7 L1 hits); per-step __syncthreads bounds drift so the 17KB step set stays in L1.
// Stage-1: 4 independent depth-8 MFMA chains (a00..a11). Stage-2: wave-private
// LDS bounce -> C2[2] accumulated over all steps -> direct store (no reduce).
// Deliberately 2 waves/SIMD: __launch_bounds__(512,2) unlocks VGPR<=256 (no spill).
struct K2A {
  const u16 *waB, *wbB, *in2T;
  const float *b2a;
  float *parts;     // [8][8192][8] f32
};

__global__ __launch_bounds__(512, 2) void k2(K2A a){
  __shared__ u16 sHw[8][2*16*40];      // per-wave 2-slab bounce (2.5KB each)
  const int bid = blockIdx.x;
  const int rg = bid>>3, ch = bid&7;
  const int tid = threadIdx.x;
  const int wid = tid>>6, lane = tid&63, c = lane&15, khi = lane>>4;

  // persistent A: this wave's 32 rows x K=256 (2 row-tiles x 8 k-tiles)
  bf16x8 Af[2][8];
  {
    const u16* aT = a.in2T + (size_t)(rg*16 + wid*2)*8*512 + lane*8;
    #pragma unroll
    for (int m=0;m<2;++m)
      #pragma unroll
      for (int kk=0;kk<8;++kk)
        Af[m][kk] = *(const bf16x8*)(aT + (size_t)(m*8+kk)*512);
  }
  f32x4 C2[2];
  C2[0]=(f32x4){0,0,0,0}; C2[1]=(f32x4){0,0,0,0};
  u16* hw = &sHw[wid][0];

  for (int cs=0; cs<40; ++cs){
    const int colb = ch*1280 + cs*32;
    const int t0 = colb>>4;
    bf16x8 Bf0[8], Bf1[8];
    #pragma unroll
    for (int kk=0;kk<8;++kk){
      Bf0[kk] = *(const bf16x8*)(a.waB + (size_t)(t0*8+kk)*512 + lane*8);
      Bf1[kk] = *(const bf16x8*)(a.waB + (size_t)((t0+1)*8+kk)*512 + lane*8);
    }
    bf16x8 B2 = *(const bf16x8*)(a.wbB + (size_t)(colb>>5)*512 + lane*8);
    const float bias0 = a.b2a[colb + c];
    const float bias1 = a.b2a[colb + 16 + c];
    f32x4 a00={0,0,0,0}, a01={0,0,0,0}, a10={0,0,0,0}, a11={0,0,0,0};
    #pragma unroll
    for (int kk=0;kk<8;++kk){
      a00 = mfma16(Af[0][kk], Bf0[kk], a00);
      a01 = mfma16(Af[0][kk], Bf1[kk], a01);
      a10 = mfma16(Af[1][kk], Bf0[kk], a10);
      a11 = mfma16(Af[1][kk], Bf1[kk], a11);
    }
    #pragma unroll
    for (int e=0;e<4;++e){
      int ro = (khi*4+e)*40;
      hw[ro + c]            = f2b(fmaxf(a00[e]+bias0, 0.f));
      hw[ro + 16 + c]       = f2b(fmaxf(a01[e]+bias1, 0.f));
      hw[640 + ro + c]      = f2b(fmaxf(a10[e]+bias0, 0.f));
      hw[640 + ro + 16 + c] = f2b(fmaxf(a11[e]+bias1, 0.f));
    }
    {
      bf16x8 A20 = *(const bf16x8*)(hw + c*40 + khi*8);
      C2[0] = mfma16(A20, B2, C2[0]);
      bf16x8 A21 = *(const bf16x8*)(hw + 640 + c*40 + khi*8);
      C2[1] = mfma16(A21, B2, C2[1]);
    }
    __syncthreads();   // pace waves together so B stays L1-shared
  }
  if (c < 8){
    #pragma unroll
    for (int m=0;m<2;++m)
      #pragma unroll
      for (int e=0;e<4;++e)
        a.parts[(size_t)ch*65536 + (size_t)(rg*256 + wid*32 + m*16 + khi*4 + e)*8 + c] = C2[m][e];
  }
}

// ---------------- K3: out2 from parts, fc3, fc4, posterior ----------------
struct K3A {
  const float *parts;
  const float *b2b, *bfc3, *bfc4, *xp, *dy, *innov;
  const u16 *in2T, *wfc3p, *wfc4p;
  float *outPost, *outHSig;
};

__global__ __launch_bounds__(256) void k3(K3A a){
  __shared__ u16 sA[64*168];
  __shared__ u16 sX4[64*168];
  __shared__ float sOut2[64*8];
  const int row0 = blockIdx.x*64;
  const int tid = threadIdx.x;
  for (int i=tid;i<512;i+=256){
    int r=i>>3, o=i&7, row=row0+r;
    float s = a.b2b[o];
    #pragma unroll
    for (int chv=0;chv<8;++chv) s += a.parts[chv*65536 + row*8 + o];
    sOut2[i]=s;
    sA[r*168+128+o]=f2b(s);
  }
  for (int i=tid;i<2048;i+=256){
    int r=i>>5, c4=i&31;
    int row = row0 + r, col = c4*4;
    *(s16x4*)(sX4 + r*168 + col) = in2t_load4(a.in2T, row, col);         // hSig
    *(s16x4*)(sA  + r*168 + col) = in2t_load4(a.in2T, row, 128 + col);   // hS_new
  }
  for (int i=tid;i<64*6;i+=256){
    int r=i/6, c4=i%6;
    *(s16x4*)(sA + r*168 + 136 + c4*4) = (s16x4){0,0,0,0};
  }
  for (int i=tid;i<64*4;i+=256){
    int r=i>>2, c4=i&3;
    *(s16x4*)(sX4 + r*168 + 144 + c4*4) = (s16x4){0,0,0,0};
  }
  __syncthreads();
  {
    int r = tid>>2, m = tid&3, row = row0+r;
    float g = 1.f/(1.f+__expf(-a.innov[0]));
    float d0 = a.dy[row*2], d1 = a.dy[row*2+1];
    float k0 = sOut2[r*8+m*2], k1 = sOut2[r*8+m*2+1];
    a.outPost[row*4+m] = a.xp[row*4+m] + g*(k0*d0+k1*d1);
  }
  const int w = tid>>6, lane = tid&63, c = lane&15, khi = lane>>4;
  {
    f32x4 C3 = {0,0,0,0};
    #pragma unroll
    for (int kk=0;kk<5;++kk){
      bf16x8 A  = *(const bf16x8*)(sA + (w*16+c)*168 + kk*32 + khi*8);
      bf16x8 Bf = *(const bf16x8*)(a.wfc3p + c*160 + kk*32 + khi*8);
      C3 = mfma16(A,Bf,C3);
    }
    float bj = a.bfc3[c];
    #pragma unroll
    for (int e=0;e<4;++e){
      int r = w*16 + khi*4 + e;
      sX4[r*168 + 128 + c] = f2b(fmaxf(C3[e]+bj, 0.f));
    }
  }
  __syncthreads();
  for (int nn=0;nn<2;++nn){
    int j = (w*2+nn)*16 + c;
    bf16x8 Bf[5];
    #pragma unroll
    for (int kk=0;kk<5;++kk) Bf[kk] = *(const bf16x8*)(a.wfc4p + j*160 + kk*32 + khi*8);
    float bj = a.bfc4[j];
    #pragma unroll
    for (int m=0;m<4;++m){
      f32x4 C = {0,0,0,0};
      #pragma unroll
      for (int kk=0;kk<5;++kk){
        bf16x8 A = *(const bf16x8*)(sX4 + (m*16+c)*168 + kk*32 + khi*8);
        C = mfma16(A, Bf[kk], C);
      }
      #pragma unroll
      for (int e=0;e<4;++e){
        int r = m*16 + khi*4 + e;
        a.outHSig[(row0+r)*128 + j] = fmaxf(C[e]+bj, 0.f);
      }
    }
  }
}

// ---------------- launcher ----------------
extern "C" void kernel_launch(void* const* d_in, const int* in_sizes, int n_in,
                              void* d_out, int out_size, void* d_ws, size_t ws_size,
                              hipStream_t stream){
  const float* y    = (const float*)d_in[0];
  const float* u    = (const float*)d_in[1];
  const float* m1x  = (const float*)d_in[2];
  const float* hQ   = (const float*)d_in[3];
  const float* hSg  = (const float*)d_in[4];
  const float* hS   = (const float*)d_in[5];
  const float* F    = (const float*)d_in[6];
  const float* G    = (const float*)d_in[7];
  const float* Hm   = (const float*)d_in[8];
  const float* innov= (const float*)d_in[9];
  const float* W5   = (const float*)d_in[10];
  const float* b5   = (const float*)d_in[11];
  const float* WihQ = (const float*)d_in[12];
  const float* WhhQ = (const float*)d_in[13];
  const float* bihQ = (const float*)d_in[14];
  const float* bhhQ = (const float*)d_in[15];
  const float* WihSg= (const float*)d_in[16];
  const float* WhhSg= (const float*)d_in[17];
  const float* bihSg= (const float*)d_in[18];
  const float* bhhSg= (const float*)d_in[19];
  const float* W1   = (const float*)d_in[20];
  const float* b1   = (const float*)d_in[21];
  const float* W7   = (const float*)d_in[22];
  const float* b7   = (const float*)d_in[23];
  const float* WihS = (const float*)d_in[24];
  const float* WhhS = (const float*)d_in[25];
  const float* bihS = (const float*)d_in[26];
  const float* bhhS = (const float*)d_in[27];
  const float* W2a  = (const float*)d_in[28];
  const float* b2a  = (const float*)d_in[29];
  const float* W2b  = (const float*)d_in[30];
  const float* b2b  = (const float*)d_in[31];
  const float* W3   = (const float*)d_in[32];
  const float* b3   = (const float*)d_in[33];
  const float* W4   = (const float*)d_in[34];
  const float* b4   = (const float*)d_in[35];

  const size_t WS_NEEDED = 12547072;
  if (ws_size < WS_NEEDED) return;

  char* ws = (char*)d_ws;
  u16*  waB   = (u16*)(ws + 0);
  u16*  wbB   = (u16*)(ws + 5242880);
  u16*  in2T  = (u16*)(ws + 5570560);
  float* parts= (float*)(ws + 9764864);     // 8*65536*4B = 2MB
  float* xp   = (float*)(ws + 11862016);
  float* dyb  = (float*)(ws + 11993088);
  u16* wihQp  = (u16*)(ws + 12058624);
  u16* whhQb  = (u16*)(ws + 12083200);
  u16* wihSgB = (u16*)(ws + 12181504);
  u16* whhSgB = (u16*)(ws + 12279808);
  u16* wihSp  = (u16*)(ws + 12378112);
  u16* whhSb  = (u16*)(ws + 12402688);
  u16* wfc3p  = (u16*)(ws + 12500992);
  u16* wfc4p  = (u16*)(ws + 12506112);

  float* outF    = (float*)d_out;
  float* outPost = outF;
  float* outHQ   = outF + 32768;
  float* outHSig = outF + 32768 + 1048576;
  float* outHS   = outF + 32768 + 2*1048576;

  CVA cv{W2a, W2b, WihQ, WhhQ, WihSg, WhhSg, WihS, WhhS, W3, W4,
         waB, wbB, wihQp, whhQb, wihSgB, whhSgB, wihSp, whhSb, wfc3p, wfc4p};
  kconv<<<dim3(11834), dim3(256), 0, stream>>>(cv);
  kconv_fc4<<<dim3(80), dim3(256), 0, stream>>>(W4, wfc4p);

  K1A a1{y,u,m1x,hQ,hSg,hS,F,G,Hm,W5,b5,bihQ,bhhQ,bihSg,bhhSg,W1,b1,W7,b7,bihS,bhhS,
         wihQp,whhQb,wihSgB,whhSgB,wihSp,whhSb,
         outHQ,outHS,xp,dyb,in2T};
  k1<<<dim3(256), dim3(256), 0, stream>>>(a1);

  K2A a2{waB, wbB, in2T, b2a, parts};
  k2<<<dim3(256), dim3(512), 0, stream>>>(a2);

  K3A a3{parts, b2b, b3, b4, xp, dyb, innov, in2T, wfc3p, wfc4p, outPost, outHSig};
  k3<<<dim3(128), dim3(256), 0, stream>>>(a3);
}

// Round 12
// 125.749 us; speedup vs baseline: 1.1941x; 1.1941x over previous
//
#include <hip/hip_runtime.h>
#include <hip/hip_bf16.h>

typedef __attribute__((ext_vector_type(8))) short bf16x8;
typedef __attribute__((ext_vector_type(4))) float f32x4;
typedef __attribute__((ext_vector_type(4))) short s16x4;
typedef __attribute__((ext_vector_type(4))) float f32v4;
typedef unsigned short u16;

__device__ inline u16 f2b(float f){ __hip_bfloat16 b = __float2bfloat16(f); return __builtin_bit_cast(unsigned short, b); }
__device__ inline float b2f(u16 u){ unsigned int x = ((unsigned int)u)<<16; return __builtin_bit_cast(float, x); }
__device__ inline float sigm(float x){ return 1.f/(1.f+__expf(-x)); }
__device__ inline float tanhfast(float x){ float e = __expf(2.f*x); return 1.f - 2.f/(e+1.f); }

__device__ inline f32x4 mfma16(bf16x8 a, bf16x8 b, f32x4 c){
  return __builtin_amdgcn_mfma_f32_16x16x32_bf16(a, b, c, 0, 0, 0);
}

// in2T fragment-tiled (R9-verified): element (row, col) at
//   ((row>>4)*8 + (col>>5))*512 + (((col>>3)&3)*16 + (row&15))*8 + (col&7)
__device__ __forceinline__ void in2t_store(u16* t, int row, int col, u16 v){
  int rt = row>>4, kk = col>>5, khi = (col>>3)&3, e = col&7;
  t[(size_t)(rt*8+kk)*512 + (khi*16 + (row&15))*8 + e] = v;
}
__device__ __forceinline__ s16x4 in2t_load4(const u16* t, int row, int col){
  int rt = row>>4, kk = col>>5, khi = (col>>3)&3, e = col&7;   // col 4-aligned
  return *(const s16x4*)(t + (size_t)(rt*8+kk)*512 + (khi*16 + (row&15))*8 + e);
}

// ---------------- weight conversion ----------------
struct CVA {
  const float *w2a, *w2b, *wihQ, *whhQ, *wihSg, *whhSg, *wihS, *whhS, *wfc3, *wfc4;
  u16 *waB, *wbB, *wihQp, *whhQb, *wihSgB, *whhSgB, *wihSp, *whhSb, *wfc3p, *wfc4p;
};

// waB tiled (R9-verified): [t=640][kk=8][lane=64][e=8];
//   (t,kk,l,e) = W2a[t*16+(l&15)][kk*32+(l>>4)*8+e]
// wbB tiled: [s=320][lane=64][e=8]; (s,l,e) = W2b[(l&15)][s*32+(l>>4)*8+e] (o>=8 -> 0)
__global__ __launch_bounds__(256) void kconv(CVA a){
  int id = blockIdx.x*256 + threadIdx.x;
  if (id < 2621440){
    int t  = id >> 12;
    int r  = id & 4095;
    int kk = r >> 9;
    int l  = (r >> 3) & 63;
    int e  = id & 7;
    int col = t*16 + (l & 15);
    int k   = kk*32 + (l >> 4)*8 + e;
    a.waB[id] = f2b(a.w2a[col*256 + k]);
    return;
  }
  id -= 2621440;
  if (id < 163840){
    int s = id >> 9;
    int r = id & 511;
    int l = r >> 3;
    int e = r & 7;
    int o = l & 15;
    int k = s*32 + (l >> 4)*8 + e;
    a.wbB[id] = (o < 8) ? f2b(a.w2b[o*10240 + k]) : (u16)0;
    return;
  }
  id -= 163840;
  if (id < 12288){ int j=id>>5, k=id&31; a.wihQp[id] = (k<20)? f2b(a.wihQ[j*20+k]) : (u16)0; return; }
  id -= 12288;
  if (id < 49152){ a.whhQb[id] = f2b(a.whhQ[id]); return; }
  id -= 49152;
  if (id < 49152){ a.wihSgB[id] = f2b(a.wihSg[id]); return; }
  id -= 49152;
  if (id < 49152){ a.whhSgB[id] = f2b(a.whhSg[id]); return; }
  id -= 49152;
  if (id < 12288){ int j=id>>5, k=id&31; a.wihSp[id] = (k<6)? f2b(a.wihS[j*6+k]) : (u16)0; return; }
  id -= 12288;
  if (id < 49152){ a.whhSb[id] = f2b(a.whhS[id]); return; }
  id -= 49152;
  if (id < 2560){ int j=id/160, k=id%160; a.wfc3p[id] = (k<136)? f2b(a.wfc3[j*136+k]) : (u16)0; return; }
}

__global__ __launch_bounds__(256) void kconv_fc4(const float* wfc4, u16* wfc4p){
  int id = blockIdx.x*256 + threadIdx.x;
  if (id < 20480){ int j=id/160, k=id%160; wfc4p[id] = (k<144)? f2b(wfc4[j*144+k]) : (u16)0; }
}

// ---------------- GRU block step (32 rows, 256 threads = 4 waves) ----------------
template<int KX, int LDX, bool SOUT, bool GB16, bool GF32>
__device__ __forceinline__ void gru_step(
    const u16* sX, const u16* sH,
    const u16* __restrict__ Wih, const int ldwih, const u16* __restrict__ Whh,
    const float* __restrict__ bih, const float* __restrict__ bhh,
    float* __restrict__ gOutF, u16* sOut,
    u16* __restrict__ in2T, int row0, int colOff)
{
  const int tid = threadIdx.x;
  const int w = tid>>6, lane = tid&63, c = lane&15, khi = lane>>4;
  for (int nn=0; nn<2; ++nn){
    const int n = w*2+nn;
    const int j = n*16 + c;
    const float bir=bih[j], biz=bih[128+j], bin=bih[256+j];
    const float bhr=bhh[j], bhz=bhh[128+j], bhn=bhh[256+j];
    bf16x8 BX0[KX], BX1[KX], BX2[KX], BH0[4], BH1[4], BH2[4];
    #pragma unroll
    for (int kk=0;kk<KX;++kk){
      const u16* p = Wih + j*ldwih + kk*32 + khi*8;
      BX0[kk] = *(const bf16x8*)(p);
      BX1[kk] = *(const bf16x8*)(p + 128*ldwih);
      BX2[kk] = *(const bf16x8*)(p + 256*ldwih);
    }
    #pragma unroll
    for (int kk=0;kk<4;++kk){
      const u16* p = Whh + j*128 + kk*32 + khi*8;
      BH0[kk] = *(const bf16x8*)(p);
      BH1[kk] = *(const bf16x8*)(p + 128*128);
      BH2[kk] = *(const bf16x8*)(p + 256*128);
    }
    #pragma unroll
    for (int m=0;m<2;++m){
      f32x4 ir={0,0,0,0}, iz={0,0,0,0}, inx={0,0,0,0};
      f32x4 hr={0,0,0,0}, hz={0,0,0,0}, hn={0,0,0,0};
      #pragma unroll
      for (int kk=0;kk<KX;++kk){
        bf16x8 A = *(const bf16x8*)(sX + (m*16+c)*LDX + kk*32 + khi*8);
        ir  = mfma16(A, BX0[kk], ir);
        iz  = mfma16(A, BX1[kk], iz);
        inx = mfma16(A, BX2[kk], inx);
      }
      #pragma unroll
      for (int kk=0;kk<4;++kk){
        bf16x8 A = *(const bf16x8*)(sH + (m*16+c)*136 + kk*32 + khi*8);
        hr = mfma16(A, BH0[kk], hr);
        hz = mfma16(A, BH1[kk], hz);
        hn = mfma16(A, BH2[kk], hn);
      }
      #pragma unroll
      for (int e=0;e<4;++e){
        int r = m*16 + khi*4 + e;
        float rg = sigm(ir[e]+hr[e]+bir+bhr);
        float zg = sigm(iz[e]+hz[e]+biz+bhz);
        float ng = tanhfast(inx[e]+bin + rg*(hn[e]+bhn));
        float hold = b2f(sH[r*136 + j]);
        float hv = (1.f-zg)*ng + zg*hold;
        if (GF32) gOutF[r*128 + j] = hv;
        if (SOUT) sOut[r*136 + j] = f2b(hv);
        if (GB16) in2t_store(in2T, row0 + r, colOff + j, f2b(hv));
      }
    }
  }
}

// ---------------- K1: chain up to in2T ----------------
struct K1A {
  const float *y,*u,*m1x,*hQ,*hSg,*hS,*F,*G,*Hm,*W5,*b5,
              *bihQ,*bhhQ,*bihSg,*bhhSg,*W1,*b1,*W7,*b7,*bihS,*bhhS;
  const u16 *wihQp,*whhQ,*wihSg,*whhSg,*wihSp,*whhS;
  float *outHQ,*outHS,*xp,*dy;
  u16 *in2T;
};

__device__ __forceinline__ void load_h_tile(u16* dst, const float* src, int row0){
  const int tid = threadIdx.x;
  #pragma unroll
  for (int i=0;i<4;++i){
    int f4 = tid + i*256;
    int r = f4>>5, c4 = f4&31;
    f32v4 v = *(const f32v4*)(src + (row0+r)*128 + c4*4);
    s16x4 o;
    o[0]=(short)f2b(v[0]); o[1]=(short)f2b(v[1]);
    o[2]=(short)f2b(v[2]); o[3]=(short)f2b(v[3]);
    *(s16x4*)(dst + r*136 + c4*4) = o;
  }
}

__global__ __launch_bounds__(256) void k1(K1A a){
  __shared__ u16 sX[32*40];
  __shared__ u16 sH[32*136];
  __shared__ u16 sXL[32*136];
  __shared__ u16 sSig[32*136];
  __shared__ float sDY[64];
  const int row0 = blockIdx.x*32;
  const int tid = threadIdx.x;

  load_h_tile(sH, a.hQ, row0);
  if (tid < 32){
    int r = tid, row = row0 + r;
    float xpost[4], uu[2], xpr[4];
    #pragma unroll
    for (int i=0;i<4;++i) xpost[i]=a.m1x[row*4+i];
    uu[0]=a.u[row*2]; uu[1]=a.u[row*2+1];
    #pragma unroll
    for (int i=0;i<4;++i){
      float s=0.f;
      #pragma unroll
      for (int jj=0;jj<4;++jj) s += a.F[i*4+jj]*xpost[jj];
      #pragma unroll
      for (int jj=0;jj<2;++jj) s += a.G[i*2+jj]*uu[jj];
      xpr[i]=s; a.xp[row*4+i]=s;
    }
    #pragma unroll
    for (int nn2=0;nn2<2;++nn2){
      float s=0.f;
      #pragma unroll
      for (int jj=0;jj<4;++jj) s += a.Hm[nn2*4+jj]*xpr[jj];
      float d = a.y[row*2+nn2]-s;
      a.dy[row*2+nn2]=d; sDY[r*2+nn2]=d;
    }
    #pragma unroll
    for (int o=0;o<20;++o){
      float s=a.b5[o];
      #pragma unroll
      for (int k=0;k<4;++k) s += a.W5[o*4+k]*xpr[k];
      sX[r*40+o]=f2b(fmaxf(s,0.f));
    }
    for (int o=20;o<40;++o) sX[r*40+o]=0;
  }
  __syncthreads();
  gru_step<1,40,true,false,true>(sX, sH, a.wihQp, 32, a.whhQ, a.bihQ, a.bhhQ,
                                 a.outHQ + row0*128, sXL, nullptr, 0, 0);
  __syncthreads();
  load_h_tile(sH, a.hSg, row0);
  __syncthreads();
  gru_step<4,136,true,true,false>(sXL, sH, a.wihSg, 128, a.whhSg, a.bihSg, a.bhhSg,
                                  nullptr, sSig, a.in2T, row0, 0);
  __syncthreads();
  if (tid < 128){
    int r = tid>>2, o = tid&3;
    float s = a.b1[o];
    for (int k=0;k<128;++k) s += a.W1[o*128+k]*b2f(sSig[r*136+k]);
    sX[r*40+o] = f2b(fmaxf(s,0.f));
  } else if (tid < 192){
    int t = tid-128; int r=t>>1, o=t&1;
    float s = a.b7[o] + a.W7[o*2]*sDY[r*2] + a.W7[o*2+1]*sDY[r*2+1];
    sX[r*40+4+o] = f2b(fmaxf(s,0.f));
  }
  for (int i=tid;i<32*26;i+=256){ int r=i/26, cc=6+(i%26); sX[r*40+cc]=0; }
  load_h_tile(sH, a.hS, row0);
  __syncthreads();
  gru_step<1,40,false,true,true>(sX, sH, a.wihSp, 32, a.whhS, a.bihS, a.bhhS,
                                 a.outHS + row0*128, nullptr, a.in2T, row0, 128);
}

// ---------------- K2: fused fc2a -> relu -> fc2b, 64x64 wave tiles ------------
// grid 512 = 64 rb x 8 ch (ch == XCD). Block: 512 thr = 8 waves (2 row-bands x
// 4 col-bands), rows rb*128..+127. A slice (128 rows x K256, 64KB) staged ONCE
// into LDS in native frag order (ds_read at lane*16B, conflict-free). Col loop:
// 5 its x 256 cols; wave tile 64x64 -> C1[4][4] (64 VGPR) per it; per k-step
// 4 ds(A) + 4 vm(B) feeds 16 MFMAs (4x arithmetic intensity vs R9). Stage-2:
// per-slab wave-private bounce -> C2[4] over all its; reduce over col-bands.
struct K2A {
  const u16 *waB, *wbB, *in2T;
  const float *b2a;
  float *parts;     // [8][8192][8] f32
};

__global__ __launch_bounds__(512, 2) void k2(K2A a){
  __shared__ u16 sA[64*512];           // 64KB: [rt=8][kk=8][512]
  __shared__ u16 sHw[8][16*72];        // 18KB per-wave slab bounce
  const int bid = blockIdx.x;
  const int rb = bid>>3, ch = bid&7;
  const int tid = threadIdx.x;
  const int wid = tid>>6, lane = tid&63, c = lane&15, khi = lane>>4;
  const int wr = wid>>2, wc = wid&3;   // 2x4 wave grid

  // stage A once: rows rb*128..+127 (row-tiles rb*8..+7, 8 k-tiles each)
  {
    const s16x4* src = (const s16x4*)(a.in2T + (size_t)rb*32768);
    s16x4* dst = (s16x4*)sA;
    #pragma unroll
    for (int i=0;i<16;++i) dst[tid + i*512] = src[tid + i*512];
  }
  __syncthreads();

  f32x4 C2[4];
  #pragma unroll
  for (int m=0;m<4;++m) C2[m] = (f32x4){0,0,0,0};
  u16* hw = &sHw[wid][0];

  for (int it=0; it<5; ++it){
    const int colb = ch*1280 + it*256 + wc*64;   // wave's 64 cols
    const int t0 = colb>>4;
    f32x4 C1[4][4];
    #pragma unroll
    for (int m=0;m<4;++m)
      #pragma unroll
      for (int n=0;n<4;++n) C1[m][n] = (f32x4){0,0,0,0};
    #pragma unroll
    for (int kk=0;kk<8;++kk){
      bf16x8 Bf[4], Ar[4];
      #pragma unroll
      for (int n=0;n<4;++n)
        Bf[n] = *(const bf16x8*)(a.waB + (size_t)((t0+n)*8+kk)*512 + lane*8);
      #pragma unroll
      for (int m=0;m<4;++m)
        Ar[m] = *(const bf16x8*)(sA + (size_t)((wr*4+m)*8+kk)*512 + lane*8);
      #pragma unroll
      for (int m=0;m<4;++m)
        #pragma unroll
        for (int n=0;n<4;++n)
          C1[m][n] = mfma16(Ar[m], Bf[n], C1[m][n]);
    }
    // epilogue: bias+relu -> bf16 slab bounce -> stage-2 MFMA (k = 64 cols)
    float bias[4];
    #pragma unroll
    for (int n=0;n<4;++n) bias[n] = a.b2a[colb + n*16 + c];
    bf16x8 B2a = *(const bf16x8*)(a.wbB + (size_t)(colb>>5)*512 + lane*8);
    bf16x8 B2b = *(const bf16x8*)(a.wbB + (size_t)((colb>>5)+1)*512 + lane*8);
    #pragma unroll
    for (int m=0;m<4;++m){
      #pragma unroll
      for (int n=0;n<4;++n)
        #pragma unroll
        for (int e=0;e<4;++e)
          hw[(khi*4+e)*72 + n*16 + c] = f2b(fmaxf(C1[m][n][e]+bias[n], 0.f));
      bf16x8 A2a = *(const bf16x8*)(hw + c*72 + khi*8);
      bf16x8 A2b = *(const bf16x8*)(hw + c*72 + 32 + khi*8);
      C2[m] = mfma16(A2a, B2a, C2[m]);
      C2[m] = mfma16(A2b, B2b, C2[m]);
    }
  }
  __syncthreads();
  float* sRed = (float*)sA;            // alias: [8 waves][64 rows][8 outs] 16KB
  if (c < 8){
    #pragma unroll
    for (int m=0;m<4;++m)
      #pragma unroll
      for (int e=0;e<4;++e)
        sRed[wid*512 + (m*16+khi*4+e)*8 + c] = C2[m][e];
  }
  __syncthreads();
  #pragma unroll
  for (int i=tid;i<1024;i+=512){
    int r=i>>3, o=i&7;
    int band=r>>6, rl=r&63;
    float s=0.f;
    #pragma unroll
    for (int w2=0;w2<4;++w2) s += sRed[(band*4+w2)*512 + rl*8 + o];
    a.parts[(size_t)ch*65536 + (size_t)(rb*128+r)*8 + o] = s;
  }
}

// ---------------- K3: out2 from parts, fc3, fc4, posterior ----------------
struct K3A {
  const float *parts;
  const float *b2b, *bfc3, *bfc4, *xp, *dy, *innov;
  const u16 *in2T, *wfc3p, *wfc4p;
  float *outPost, *outHSig;
};

__global__ __launch_bounds__(256) void k3(K3A a){
  __shared__ u16 sA[64*168];
  __shared__ u16 sX4[64*168];
  __shared__ float sOut2[64*8];
  const int row0 = blockIdx.x*64;
  const int tid = threadIdx.x;
  for (int i=tid;i<512;i+=256){
    int r=i>>3, o=i&7, row=row0+r;
    float s = a.b2b[o];
    #pragma unroll
    for (int chv=0;chv<8;++chv) s += a.parts[chv*65536 + row*8 + o];
    sOut2[i]=s;
    sA[r*168+128+o]=f2b(s);
  }
  for (int i=tid;i<2048;i+=256){
    int r=i>>5, c4=i&31;
    int row = row0 + r, col = c4*4;
    *(s16x4*)(sX4 + r*168 + col) = in2t_load4(a.in2T, row, col);         // hSig
    *(s16x4*)(sA  + r*168 + col) = in2t_load4(a.in2T, row, 128 + col);   // hS_new
  }
  for (int i=tid;i<64*6;i+=256){
    int r=i/6, c4=i%6;
    *(s16x4*)(sA + r*168 + 136 + c4*4) = (s16x4){0,0,0,0};
  }
  for (int i=tid;i<64*4;i+=256){
    int r=i>>2, c4=i&3;
    *(s16x4*)(sX4 + r*168 + 144 + c4*4) = (s16x4){0,0,0,0};
  }
  __syncthreads();
  {
    int r = tid>>2, m = tid&3, row = row0+r;
    float g = 1.f/(1.f+__expf(-a.innov[0]));
    float d0 = a.dy[row*2], d1 = a.dy[row*2+1];
    float k0 = sOut2[r*8+m*2], k1 = sOut2[r*8+m*2+1];
    a.outPost[row*4+m] = a.xp[row*4+m] + g*(k0*d0+k1*d1);
  }
  const int w = tid>>6, lane = tid&63, c = lane&15, khi = lane>>4;
  {
    f32x4 C3 = {0,0,0,0};
    #pragma unroll
    for (int kk=0;kk<5;++kk){
      bf16x8 A  = *(const bf16x8*)(sA + (w*16+c)*168 + kk*32 + khi*8);
      bf16x8 Bf = *(const bf16x8*)(a.wfc3p + c*160 + kk*32 + khi*8);
      C3 = mfma16(A,Bf,C3);
    }
    float bj = a.bfc3[c];
    #pragma unroll
    for (int e=0;e<4;++e){
      int r = w*16 + khi*4 + e;
      sX4[r*168 + 128 + c] = f2b(fmaxf(C3[e]+bj, 0.f));
    }
  }
  __syncthreads();
  for (int nn=0;nn<2;++nn){
    int j = (w*2+nn)*16 + c;
    bf16x8 Bf[5];
    #pragma unroll
    for (int kk=0;kk<5;++kk) Bf[kk] = *(const bf16x8*)(a.wfc4p + j*160 + kk*32 + khi*8);
    float bj = a.bfc4[j];
    #pragma unroll
    for (int m=0;m<4;++m){
      f32x4 C = {0,0,0,0};
      #pragma unroll
      for (int kk=0;kk<5;++kk){
        bf16x8 A = *(const bf16x8*)(sX4 + (m*16+c)*168 + kk*32 + khi*8);
        C = mfma16(A, Bf[kk], C);
      }
      #pragma unroll
      for (int e=0;e<4;++e){
        int r = m*16 + khi*4 + e;
        a.outHSig[(row0+r)*128 + j] = fmaxf(C[e]+bj, 0.f);
      }
    }
  }
}

// ---------------- launcher ----------------
extern "C" void kernel_launch(void* const* d_in, const int* in_sizes, int n_in,
                              void* d_out, int out_size, void* d_ws, size_t ws_size,
                              hipStream_t stream){
  const float* y    = (const float*)d_in[0];
  const float* u    = (const float*)d_in[1];
  const float* m1x  = (const float*)d_in[2];
  const float* hQ   = (const float*)d_in[3];
  const float* hSg  = (const float*)d_in[4];
  const float* hS   = (const float*)d_in[5];
  const float* F    = (const float*)d_in[6];
  const float* G    = (const float*)d_in[7];
  const float* Hm   = (const float*)d_in[8];
  const float* innov= (const float*)d_in[9];
  const float* W5   = (const float*)d_in[10];
  const float* b5   = (const float*)d_in[11];
  const float* WihQ = (const float*)d_in[12];
  const float* WhhQ = (const float*)d_in[13];
  const float* bihQ = (const float*)d_in[14];
  const float* bhhQ = (const float*)d_in[15];
  const float* WihSg= (const float*)d_in[16];
  const float* WhhSg= (const float*)d_in[17];
  const float* bihSg= (const float*)d_in[18];
  const float* bhhSg= (const float*)d_in[19];
  const float* W1   = (const float*)d_in[20];
  const float* b1   = (const float*)d_in[21];
  const float* W7   = (const float*)d_in[22];
  const float* b7   = (const float*)d_in[23];
  const float* WihS = (const float*)d_in[24];
  const float* WhhS = (const float*)d_in[25];
  const float* bihS = (const float*)d_in[26];
  const float* bhhS = (const float*)d_in[27];
  const float* W2a  = (const float*)d_in[28];
  const float* b2a  = (const float*)d_in[29];
  const float* W2b  = (const float*)d_in[30];
  const float* b2b  = (const float*)d_in[31];
  const float* W3   = (const float*)d_in[32];
  const float* b3   = (const float*)d_in[33];
  const float* W4   = (const float*)d_in[34];
  const float* b4   = (const float*)d_in[35];

  const size_t WS_NEEDED = 12547072;
  if (ws_size < WS_NEEDED) return;

  char* ws = (char*)d_ws;
  u16*  waB   = (u16*)(ws + 0);
  u16*  wbB   = (u16*)(ws + 5242880);
  u16*  in2T  = (u16*)(ws + 5570560);
  float* parts= (float*)(ws + 9764864);     // 8*65536*4B = 2MB
  float* xp   = (float*)(ws + 11862016);
  float* dyb  = (float*)(ws + 11993088);
  u16* wihQp  = (u16*)(ws + 12058624);
  u16* whhQb  = (u16*)(ws + 12083200);
  u16* wihSgB = (u16*)(ws + 12181504);
  u16* whhSgB = (u16*)(ws + 12279808);
  u16* wihSp  = (u16*)(ws + 12378112);
  u16* whhSb  = (u16*)(ws + 12402688);
  u16* wfc3p  = (u16*)(ws + 12500992);
  u16* wfc4p  = (u16*)(ws + 12506112);

  float* outF    = (float*)d_out;
  float* outPost = outF;
  float* outHQ   = outF + 32768;
  float* outHSig = outF + 32768 + 1048576;
  float* outHS   = outF + 32768 + 2*1048576;

  CVA cv{W2a, W2b, WihQ, WhhQ, WihSg, WhhSg, WihS, WhhS, W3, W4,
         waB, wbB, wihQp, whhQb, wihSgB, whhSgB, wihSp, whhSb, wfc3p, wfc4p};
  kconv<<<dim3(11834), dim3(256), 0, stream>>>(cv);
  kconv_fc4<<<dim3(80), dim3(256), 0, stream>>>(W4, wfc4p);

  K1A a1{y,u,m1x,hQ,hSg,hS,F,G,Hm,W5,b5,bihQ,bhhQ,bihSg,bhhSg,W1,b1,W7,b7,bihS,bhhS,
         wihQp,whhQb,wihSgB,whhSgB,wihSp,whhSb,
         outHQ,outHS,xp,dyb,in2T};
  k1<<<dim3(256), dim3(256), 0, stream>>>(a1);

  K2A a2{waB, wbB, in2T, b2a, parts};
  k2<<<dim3(512), dim3(512), 0, stream>>>(a2);

  K3A a3{parts, b2b, b3, b4, xp, dyb, innov, in2T, wfc3p, wfc4p, outPost, outHSig};
  k3<<<dim3(128), dim3(256), 0, stream>>>(a3);
}

// Round 13
// 100.803 us; speedup vs baseline: 1.4896x; 1.2475x over previous
//
#include <hip/hip_runtime.h>
#include <hip/hip_bf16.h>

typedef __attribute__((ext_vector_type(8))) short bf16x8;
typedef __attribute__((ext_vector_type(4))) float f32x4;
typedef __attribute__((ext_vector_type(4))) short s16x4;
typedef __attribute__((ext_vector_type(4))) float f32v4;
typedef unsigned short u16;
typedef unsigned int u32;

__device__ inline u16 f2b(float f){ __hip_bfloat16 b = __float2bfloat16(f); return __builtin_bit_cast(unsigned short, b); }
__device__ inline float b2f(u16 u){ unsigned int x = ((unsigned int)u)<<16; return __builtin_bit_cast(float, x); }
__device__ inline float sigm(float x){ return 1.f/(1.f+__expf(-x)); }
__device__ inline float tanhfast(float x){ float e = __expf(2.f*x); return 1.f - 2.f/(e+1.f); }

__device__ inline f32x4 mfma16(bf16x8 a, bf16x8 b, f32x4 c){
  return __builtin_amdgcn_mfma_f32_16x16x32_bf16(a, b, c, 0, 0, 0);
}

// in2T fragment-tiled (R9-verified): element (row, col) at
//   ((row>>4)*8 + (col>>5))*512 + (((col>>3)&3)*16 + (row&15))*8 + (col&7)
__device__ __forceinline__ void in2t_store(u16* t, int row, int col, u16 v){
  int rt = row>>4, kk = col>>5, khi = (col>>3)&3, e = col&7;
  t[(size_t)(rt*8+kk)*512 + (khi*16 + (row&15))*8 + e] = v;
}
__device__ __forceinline__ s16x4 in2t_load4(const u16* t, int row, int col){
  int rt = row>>4, kk = col>>5, khi = (col>>3)&3, e = col&7;   // col 4-aligned
  return *(const s16x4*)(t + (size_t)(rt*8+kk)*512 + (khi*16 + (row&15))*8 + e);
}

// ---------------- weight conversion ----------------
struct CVA {
  const float *w2a, *w2b, *wihQ, *whhQ, *wihSg, *whhSg, *wihS, *whhS, *wfc3, *wfc4;
  u16 *waB, *wbB, *wihQp, *whhQb, *wihSgB, *whhSgB, *wihSp, *whhSb, *wfc3p, *wfc4p;
};

// waB tiled (R9-verified): [t=640][kk=8][lane=64][e=8];
//   (t,kk,l,e) = W2a[t*16+(l&15)][kk*32+(l>>4)*8+e]
// wbB tiled + PERMUTED hidden order (matches k2's paired-u32 bounce):
//   q=(l>>4)*8+e; (s,l,e) = W2b[(l&15)][s*32 + (q&1)*16 + (q>>1)]  (o>=8 -> 0)
__global__ __launch_bounds__(256) void kconv(CVA a){
  int id = blockIdx.x*256 + threadIdx.x;
  if (id < 2621440){
    int t  = id >> 12;
    int r  = id & 4095;
    int kk = r >> 9;
    int l  = (r >> 3) & 63;
    int e  = id & 7;
    int col = t*16 + (l & 15);
    int k   = kk*32 + (l >> 4)*8 + e;
    a.waB[id] = f2b(a.w2a[col*256 + k]);
    return;
  }
  id -= 2621440;
  if (id < 163840){
    int s = id >> 9;
    int r = id & 511;
    int l = r >> 3;
    int e = r & 7;
    int o = l & 15;
    int q = (l >> 4)*8 + e;
    int k = s*32 + (q&1)*16 + (q>>1);
    a.wbB[id] = (o < 8) ? f2b(a.w2b[o*10240 + k]) : (u16)0;
    return;
  }
  id -= 163840;
  if (id < 12288){ int j=id>>5, k=id&31; a.wihQp[id] = (k<20)? f2b(a.wihQ[j*20+k]) : (u16)0; return; }
  id -= 12288;
  if (id < 49152){ a.whhQb[id] = f2b(a.whhQ[id]); return; }
  id -= 49152;
  if (id < 49152){ a.wihSgB[id] = f2b(a.wihSg[id]); return; }
  id -= 49152;
  if (id < 49152){ a.whhSgB[id] = f2b(a.whhSg[id]); return; }
  id -= 49152;
  if (id < 12288){ int j=id>>5, k=id&31; a.wihSp[id] = (k<6)? f2b(a.wihS[j*6+k]) : (u16)0; return; }
  id -= 12288;
  if (id < 49152){ a.whhSb[id] = f2b(a.whhS[id]); return; }
  id -= 49152;
  if (id < 2560){ int j=id/160, k=id%160; a.wfc3p[id] = (k<136)? f2b(a.wfc3[j*136+k]) : (u16)0; return; }
}

__global__ __launch_bounds__(256) void kconv_fc4(const float* wfc4, u16* wfc4p){
  int id = blockIdx.x*256 + threadIdx.x;
  if (id < 20480){ int j=id/160, k=id%160; wfc4p[id] = (k<144)? f2b(wfc4[j*144+k]) : (u16)0; }
}

// ---------------- GRU block step (32 rows, 256 threads = 4 waves) ----------------
template<int KX, int LDX, bool SOUT, bool GB16, bool GF32>
__device__ __forceinline__ void gru_step(
    const u16* sX, const u16* sH,
    const u16* __restrict__ Wih, const int ldwih, const u16* __restrict__ Whh,
    const float* __restrict__ bih, const float* __restrict__ bhh,
    float* __restrict__ gOutF, u16* sOut,
    u16* __restrict__ in2T, int row0, int colOff)
{
  const int tid = threadIdx.x;
  const int w = tid>>6, lane = tid&63, c = lane&15, khi = lane>>4;
  for (int nn=0; nn<2; ++nn){
    const int n = w*2+nn;
    const int j = n*16 + c;
    const float bir=bih[j], biz=bih[128+j], bin=bih[256+j];
    const float bhr=bhh[j], bhz=bhh[128+j], bhn=bhh[256+j];
    bf16x8 BX0[KX], BX1[KX], BX2[KX], BH0[4], BH1[4], BH2[4];
    #pragma unroll
    for (int kk=0;kk<KX;++kk){
      const u16* p = Wih + j*ldwih + kk*32 + khi*8;
      BX0[kk] = *(const bf16x8*)(p);
      BX1[kk] = *(const bf16x8*)(p + 128*ldwih);
      BX2[kk] = *(const bf16x8*)(p + 256*ldwih);
    }
    #pragma unroll
    for (int kk=0;kk<4;++kk){
      const u16* p = Whh + j*128 + kk*32 + khi*8;
      BH0[kk] = *(const bf16x8*)(p);
      BH1[kk] = *(const bf16x8*)(p + 128*128);
      BH2[kk] = *(const bf16x8*)(p + 256*128);
    }
    #pragma unroll
    for (int m=0;m<2;++m){
      f32x4 ir={0,0,0,0}, iz={0,0,0,0}, inx={0,0,0,0};
      f32x4 hr={0,0,0,0}, hz={0,0,0,0}, hn={0,0,0,0};
      #pragma unroll
      for (int kk=0;kk<KX;++kk){
        bf16x8 A = *(const bf16x8*)(sX + (m*16+c)*LDX + kk*32 + khi*8);
        ir  = mfma16(A, BX0[kk], ir);
        iz  = mfma16(A, BX1[kk], iz);
        inx = mfma16(A, BX2[kk], inx);
      }
      #pragma unroll
      for (int kk=0;kk<4;++kk){
        bf16x8 A = *(const bf16x8*)(sH + (m*16+c)*136 + kk*32 + khi*8);
        hr = mfma16(A, BH0[kk], hr);
        hz = mfma16(A, BH1[kk], hz);
        hn = mfma16(A, BH2[kk], hn);
      }
      #pragma unroll
      for (int e=0;e<4;++e){
        int r = m*16 + khi*4 + e;
        float rg = sigm(ir[e]+hr[e]+bir+bhr);
        float zg = sigm(iz[e]+hz[e]+biz+bhz);
        float ng = tanhfast(inx[e]+bin + rg*(hn[e]+bhn));
        float hold = b2f(sH[r*136 + j]);
        float hv = (1.f-zg)*ng + zg*hold;
        if (GF32) gOutF[r*128 + j] = hv;
        if (SOUT) sOut[r*136 + j] = f2b(hv);
        if (GB16) in2t_store(in2T, row0 + r, colOff + j, f2b(hv));
      }
    }
  }
}

// ---------------- K1: chain up to in2T ----------------
struct K1A {
  const float *y,*u,*m1x,*hQ,*hSg,*hS,*F,*G,*Hm,*W5,*b5,
              *bihQ,*bhhQ,*bihSg,*bhhSg,*W1,*b1,*W7,*b7,*bihS,*bhhS;
  const u16 *wihQp,*whhQ,*wihSg,*whhSg,*wihSp,*whhS;
  float *outHQ,*outHS,*xp,*dy;
  u16 *in2T;
};

__device__ __forceinline__ void load_h_tile(u16* dst, const float* src, int row0){
  const int tid = threadIdx.x;
  #pragma unroll
  for (int i=0;i<4;++i){
    int f4 = tid + i*256;
    int r = f4>>5, c4 = f4&31;
    f32v4 v = *(const f32v4*)(src + (row0+r)*128 + c4*4);
    s16x4 o;
    o[0]=(short)f2b(v[0]); o[1]=(short)f2b(v[1]);
    o[2]=(short)f2b(v[2]); o[3]=(short)f2b(v[3]);
    *(s16x4*)(dst + r*136 + c4*4) = o;
  }
}

__global__ __launch_bounds__(256) void k1(K1A a){
  __shared__ u16 sX[32*40];
  __shared__ u16 sH[32*136];
  __shared__ u16 sXL[32*136];
  __shared__ u16 sSig[32*136];
  __shared__ float sDY[64];
  const int row0 = blockIdx.x*32;
  const int tid = threadIdx.x;

  load_h_tile(sH, a.hQ, row0);
  if (tid < 32){
    int r = tid, row = row0 + r;
    float xpost[4], uu[2], xpr[4];
    #pragma unroll
    for (int i=0;i<4;++i) xpost[i]=a.m1x[row*4+i];
    uu[0]=a.u[row*2]; uu[1]=a.u[row*2+1];
    #pragma unroll
    for (int i=0;i<4;++i){
      float s=0.f;
      #pragma unroll
      for (int jj=0;jj<4;++jj) s += a.F[i*4+jj]*xpost[jj];
      #pragma unroll
      for (int jj=0;jj<2;++jj) s += a.G[i*2+jj]*uu[jj];
      xpr[i]=s; a.xp[row*4+i]=s;
    }
    #pragma unroll
    for (int nn2=0;nn2<2;++nn2){
      float s=0.f;
      #pragma unroll
      for (int jj=0;jj<4;++jj) s += a.Hm[nn2*4+jj]*xpr[jj];
      float d = a.y[row*2+nn2]-s;
      a.dy[row*2+nn2]=d; sDY[r*2+nn2]=d;
    }
    #pragma unroll
    for (int o=0;o<20;++o){
      float s=a.b5[o];
      #pragma unroll
      for (int k=0;k<4;++k) s += a.W5[o*4+k]*xpr[k];
      sX[r*40+o]=f2b(fmaxf(s,0.f));
    }
    for (int o=20;o<40;++o) sX[r*40+o]=0;
  }
  __syncthreads();
  gru_step<1,40,true,false,true>(sX, sH, a.wihQp, 32, a.whhQ, a.bihQ, a.bhhQ,
                                 a.outHQ + row0*128, sXL, nullptr, 0, 0);
  __syncthreads();
  load_h_tile(sH, a.hSg, row0);
  __syncthreads();
  gru_step<4,136,true,true,false>(sXL, sH, a.wihSg, 128, a.whhSg, a.bihSg, a.bhhSg,
                                  nullptr, sSig, a.in2T, row0, 0);
  __syncthreads();
  if (tid < 128){
    int r = tid>>2, o = tid&3;
    float s = a.b1[o];
    for (int k=0;k<128;++k) s += a.W1[o*128+k]*b2f(sSig[r*136+k]);
    sX[r*40+o] = f2b(fmaxf(s,0.f));
  } else if (tid < 192){
    int t = tid-128; int r=t>>1, o=t&1;
    float s = a.b7[o] + a.W7[o*2]*sDY[r*2] + a.W7[o*2+1]*sDY[r*2+1];
    sX[r*40+4+o] = f2b(fmaxf(s,0.f));
  }
  for (int i=tid;i<32*26;i+=256){ int r=i/26, cc=6+(i%26); sX[r*40+cc]=0; }
  load_h_tile(sH, a.hS, row0);
  __syncthreads();
  gru_step<1,40,false,true,true>(sX, sH, a.wihSp, 32, a.whhS, a.bihS, a.bhhS,
                                 a.outHS + row0*128, nullptr, a.in2T, row0, 128);
}

// ---------------- K2: fused fc2a -> relu -> fc2b, 64x32 wave tiles ------------
// grid 512 = 64 rb x 8 ch (ch == XCD). Block: 512 thr = 8 waves (2 row-bands x
// 4 col-bands), rows rb*128..+127 staged ONCE in LDS (64KB, native frag order,
// ds_read at lane*16B conflict-free). 10 its x 128 cols: wave tile 64x32 ->
// C1[4][2] (32 VGPR, live set ~90 -> NO spill). Per k-step 4 ds(A) + 2 vm(B)
// feeds 8 MFMAs. Epilogue: paired-u32 bounce writes (hidden order permuted,
// wbB matches) -> stage-2 mfma16 into C2[4]; reduce over col-band waves.
struct K2A {
  const u16 *waB, *wbB, *in2T;
  const float *b2a;
  float *parts;     // [8][8192][8] f32
};

__global__ __launch_bounds__(512) void k2(K2A a){
  __shared__ u16 sA[128*256];          // 64KB: [rt=8][kk=8][512]
  __shared__ u16 sHw[8][16*40];        // 10KB per-wave slab bounce
  const int bid = blockIdx.x;
  const int rb = bid>>3, ch = bid&7;
  const int tid = threadIdx.x;
  const int wid = tid>>6, lane = tid&63, c = lane&15, khi = lane>>4;
  const int wr = wid>>2, wc = wid&3;   // 2 row-bands x 4 col-bands

  // stage A once: rows rb*128..+127 (row-tiles 8, 8 k-tiles each)
  {
    const s16x4* src = (const s16x4*)(a.in2T + (size_t)rb*32768);
    s16x4* dst = (s16x4*)sA;
    #pragma unroll
    for (int i=0;i<16;++i) dst[tid + i*512] = src[tid + i*512];
  }
  __syncthreads();

  f32x4 C2[4];
  #pragma unroll
  for (int m=0;m<4;++m) C2[m] = (f32x4){0,0,0,0};
  u16* hw = &sHw[wid][0];

  for (int it=0; it<10; ++it){
    const int colb = ch*1280 + it*128 + wc*32;   // wave's 32 cols
    const int t0 = colb>>4;
    f32x4 C1[4][2];
    #pragma unroll
    for (int m=0;m<4;++m){ C1[m][0]=(f32x4){0,0,0,0}; C1[m][1]=(f32x4){0,0,0,0}; }
    #pragma unroll
    for (int kk=0;kk<8;++kk){
      bf16x8 Bf0 = *(const bf16x8*)(a.waB + (size_t)(t0*8+kk)*512 + lane*8);
      bf16x8 Bf1 = *(const bf16x8*)(a.waB + (size_t)((t0+1)*8+kk)*512 + lane*8);
      #pragma unroll
      for (int m=0;m<4;++m){
        bf16x8 Ar = *(const bf16x8*)(sA + (size_t)((wr*4+m)*8+kk)*512 + lane*8);
        C1[m][0] = mfma16(Ar, Bf0, C1[m][0]);
        C1[m][1] = mfma16(Ar, Bf1, C1[m][1]);
      }
    }
    // epilogue: bias+relu -> paired u32 bounce (permuted cols) -> stage-2
    bf16x8 B2 = *(const bf16x8*)(a.wbB + (size_t)(colb>>5)*512 + lane*8);
    const float bias0 = a.b2a[colb + c];
    const float bias1 = a.b2a[colb + 16 + c];
    #pragma unroll
    for (int m=0;m<4;++m){
      #pragma unroll
      for (int e=0;e<4;++e){
        float v0 = fmaxf(C1[m][0][e]+bias0, 0.f);
        float v1 = fmaxf(C1[m][1][e]+bias1, 0.f);
        u32 w = (u32)f2b(v0) | ((u32)f2b(v1)<<16);
        *(u32*)(hw + (khi*4+e)*40 + 2*c) = w;
      }
      bf16x8 A2 = *(const bf16x8*)(hw + c*40 + khi*8);
      C2[m] = mfma16(A2, B2, C2[m]);
    }
  }
  __syncthreads();
  float* sRed = (float*)sA;            // alias: [8 waves][64 rows][8 outs] 16KB
  if (c < 8){
    #pragma unroll
    for (int m=0;m<4;++m)
      #pragma unroll
      for (int e=0;e<4;++e)
        sRed[wid*512 + (m*16+khi*4+e)*8 + c] = C2[m][e];
  }
  __syncthreads();
  #pragma unroll
  for (int i=tid;i<1024;i+=512){
    int r=i>>3, o=i&7;
    int band=r>>6, rl=r&63;
    float s=0.f;
    #pragma unroll
    for (int w2=0;w2<4;++w2) s += sRed[(band*4+w2)*512 + rl*8 + o];
    a.parts[(size_t)ch*65536 + (size_t)(rb*128+r)*8 + o] = s;
  }
}

// ---------------- K3: out2 from parts, fc3, fc4, posterior ----------------
struct K3A {
  const float *parts;
  const float *b2b, *bfc3, *bfc4, *xp, *dy, *innov;
  const u16 *in2T, *wfc3p, *wfc4p;
  float *outPost, *outHSig;
};

__global__ __launch_bounds__(256) void k3(K3A a){
  __shared__ u16 sA[64*168];
  __shared__ u16 sX4[64*168];
  __shared__ float sOut2[64*8];
  const int row0 = blockIdx.x*64;
  const int tid = threadIdx.x;
  for (int i=tid;i<512;i+=256){
    int r=i>>3, o=i&7, row=row0+r;
    float s = a.b2b[o];
    #pragma unroll
    for (int chv=0;chv<8;++chv) s += a.parts[chv*65536 + row*8 + o];
    sOut2[i]=s;
    sA[r*168+128+o]=f2b(s);
  }
  for (int i=tid;i<2048;i+=256){
    int r=i>>5, c4=i&31;
    int row = row0 + r, col = c4*4;
    *(s16x4*)(sX4 + r*168 + col) = in2t_load4(a.in2T, row, col);         // hSig
    *(s16x4*)(sA  + r*168 + col) = in2t_load4(a.in2T, row, 128 + col);   // hS_new
  }
  for (int i=tid;i<64*6;i+=256){
    int r=i/6, c4=i%6;
    *(s16x4*)(sA + r*168 + 136 + c4*4) = (s16x4){0,0,0,0};
  }
  for (int i=tid;i<64*4;i+=256){
    int r=i>>2, c4=i&3;
    *(s16x4*)(sX4 + r*168 + 144 + c4*4) = (s16x4){0,0,0,0};
  }
  __syncthreads();
  {
    int r = tid>>2, m = tid&3, row = row0+r;
    float g = 1.f/(1.f+__expf(-a.innov[0]));
    float d0 = a.dy[row*2], d1 = a.dy[row*2+1];
    float k0 = sOut2[r*8+m*2], k1 = sOut2[r*8+m*2+1];
    a.outPost[row*4+m] = a.xp[row*4+m] + g*(k0*d0+k1*d1);
  }
  const int w = tid>>6, lane = tid&63, c = lane&15, khi = lane>>4;
  {
    f32x4 C3 = {0,0,0,0};
    #pragma unroll
    for (int kk=0;kk<5;++kk){
      bf16x8 A  = *(const bf16x8*)(sA + (w*16+c)*168 + kk*32 + khi*8);
      bf16x8 Bf = *(const bf16x8*)(a.wfc3p + c*160 + kk*32 + khi*8);
      C3 = mfma16(A,Bf,C3);
    }
    float bj = a.bfc3[c];
    #pragma unroll
    for (int e=0;e<4;++e){
      int r = w*16 + khi*4 + e;
      sX4[r*168 + 128 + c] = f2b(fmaxf(C3[e]+bj, 0.f));
    }
  }
  __syncthreads();
  for (int nn=0;nn<2;++nn){
    int j = (w*2+nn)*16 + c;
    bf16x8 Bf[5];
    #pragma unroll
    for (int kk=0;kk<5;++kk) Bf[kk] = *(const bf16x8*)(a.wfc4p + j*160 + kk*32 + khi*8);
    float bj = a.bfc4[j];
    #pragma unroll
    for (int m=0;m<4;++m){
      f32x4 C = {0,0,0,0};
      #pragma unroll
      for (int kk=0;kk<5;++kk){
        bf16x8 A = *(const bf16x8*)(sX4 + (m*16+c)*168 + kk*32 + khi*8);
        C = mfma16(A, Bf[kk], C);
      }
      #pragma unroll
      for (int e=0;e<4;++e){
        int r = m*16 + khi*4 + e;
        a.outHSig[(row0+r)*128 + j] = fmaxf(C[e]+bj, 0.f);
      }
    }
  }
}

// ---------------- launcher ----------------
extern "C" void kernel_launch(void* const* d_in, const int* in_sizes, int n_in,
                              void* d_out, int out_size, void* d_ws, size_t ws_size,
                              hipStream_t stream){
  const float* y    = (const float*)d_in[0];
  const float* u    = (const float*)d_in[1];
  const float* m1x  = (const float*)d_in[2];
  const float* hQ   = (const float*)d_in[3];
  const float* hSg  = (const float*)d_in[4];
  const float* hS   = (const float*)d_in[5];
  const float* F    = (const float*)d_in[6];
  const float* G    = (const float*)d_in[7];
  const float* Hm   = (const float*)d_in[8];
  const float* innov= (const float*)d_in[9];
  const float* W5   = (const float*)d_in[10];
  const float* b5   = (const float*)d_in[11];
  const float* WihQ = (const float*)d_in[12];
  const float* WhhQ = (const float*)d_in[13];
  const float* bihQ = (const float*)d_in[14];
  const float* bhhQ = (const float*)d_in[15];
  const float* WihSg= (const float*)d_in[16];
  const float* WhhSg= (const float*)d_in[17];
  const float* bihSg= (const float*)d_in[18];
  const float* bhhSg= (const float*)d_in[19];
  const float* W1   = (const float*)d_in[20];
  const float* b1   = (const float*)d_in[21];
  const float* W7   = (const float*)d_in[22];
  const float* b7   = (const float*)d_in[23];
  const float* WihS = (const float*)d_in[24];
  const float* WhhS = (const float*)d_in[25];
  const float* bihS = (const float*)d_in[26];
  const float* bhhS = (const float*)d_in[27];
  const float* W2a  = (const float*)d_in[28];
  const float* b2a  = (const float*)d_in[29];
  const float* W2b  = (const float*)d_in[30];
  const float* b2b  = (const float*)d_in[31];
  const float* W3   = (const float*)d_in[32];
  const float* b3   = (const float*)d_in[33];
  const float* W4   = (const float*)d_in[34];
  const float* b4   = (const float*)d_in[35];

  const size_t WS_NEEDED = 12547072;
  if (ws_size < WS_NEEDED) return;

  char* ws = (char*)d_ws;
  u16*  waB   = (u16*)(ws + 0);
  u16*  wbB   = (u16*)(ws + 5242880);
  u16*  in2T  = (u16*)(ws + 5570560);
  float* parts= (float*)(ws + 9764864);     // 8*65536*4B = 2MB
  float* xp   = (float*)(ws + 11862016);
  float* dyb  = (float*)(ws + 11993088);
  u16* wihQp  = (u16*)(ws + 12058624);
  u16* whhQb  = (u16*)(ws + 12083200);
  u16* wihSgB = (u16*)(ws + 12181504);
  u16* whhSgB = (u16*)(ws + 12279808);
  u16* wihSp  = (u16*)(ws + 12378112);
  u16* whhSb  = (u16*)(ws + 12402688);
  u16* wfc3p  = (u16*)(ws + 12500992);
  u16* wfc4p  = (u16*)(ws + 12506112);

  float* outF    = (float*)d_out;
  float* outPost = outF;
  float* outHQ   = outF + 32768;
  float* outHSig = outF + 32768 + 1048576;
  float* outHS   = outF + 32768 + 2*1048576;

  CVA cv{W2a, W2b, WihQ, WhhQ, WihSg, WhhSg, WihS, WhhS, W3, W4,
         waB, wbB, wihQp, whhQb, wihSgB, whhSgB, wihSp, whhSb, wfc3p, wfc4p};
  kconv<<<dim3(11834), dim3(256), 0, stream>>>(cv);
  kconv_fc4<<<dim3(80), dim3(256), 0, stream>>>(W4, wfc4p);

  K1A a1{y,u,m1x,hQ,hSg,hS,F,G,Hm,W5,b5,bihQ,bhhQ,bihSg,bhhSg,W1,b1,W7,b7,bihS,bhhS,
         wihQp,whhQb,wihSgB,whhSgB,wihSp,whhSb,
         outHQ,outHS,xp,dyb,in2T};
  k1<<<dim3(256), dim3(256), 0, stream>>>(a1);

  K2A a2{waB, wbB, in2T, b2a, parts};
  k2<<<dim3(512), dim3(512), 0, stream>>>(a2);

  K3A a3{parts, b2b, b3, b4, xp, dyb, innov, in2T, wfc3p, wfc4p, outPost, outHSig};
  k3<<<dim3(128), dim3(256), 0, stream>>>(a3);
}

// Round 14
// 93.018 us; speedup vs baseline: 1.6143x; 1.0837x over previous
//
#include <hip/hip_runtime.h>
#include <hip/hip_bf16.h>

typedef __attribute__((ext_vector_type(8))) short bf16x8;
typedef __attribute__((ext_vector_type(4))) float f32x4;
typedef __attribute__((ext_vector_type(4))) short s16x4;
typedef __attribute__((ext_vector_type(4))) float f32v4;
typedef unsigned short u16;
typedef unsigned int u32;

__device__ inline u16 f2b(float f){ __hip_bfloat16 b = __float2bfloat16(f); return __builtin_bit_cast(unsigned short, b); }
__device__ inline float b2f(u16 u){ unsigned int x = ((unsigned int)u)<<16; return __builtin_bit_cast(float, x); }
__device__ inline float sigm(float x){ return 1.f/(1.f+__expf(-x)); }
__device__ inline float tanhfast(float x){ float e = __expf(2.f*x); return 1.f - 2.f/(e+1.f); }

__device__ inline f32x4 mfma16(bf16x8 a, bf16x8 b, f32x4 c){
  return __builtin_amdgcn_mfma_f32_16x16x32_bf16(a, b, c, 0, 0, 0);
}

// in2T fragment-tiled (R9-verified): element (row, col) at
//   ((row>>4)*8 + (col>>5))*512 + (((col>>3)&3)*16 + (row&15))*8 + (col&7)
__device__ __forceinline__ void in2t_store(u16* t, int row, int col, u16 v){
  int rt = row>>4, kk = col>>5, khi = (col>>3)&3, e = col&7;
  t[(size_t)(rt*8+kk)*512 + (khi*16 + (row&15))*8 + e] = v;
}
__device__ __forceinline__ s16x4 in2t_load4(const u16* t, int row, int col){
  int rt = row>>4, kk = col>>5, khi = (col>>3)&3, e = col&7;   // col 4-aligned
  return *(const s16x4*)(t + (size_t)(rt*8+kk)*512 + (khi*16 + (row&15))*8 + e);
}

// ---------------- weight conversion (coalesced, 8 elem/thread for big arrays) --
struct CVA {
  const float *w2a, *w2b, *wihQ, *whhQ, *wihSg, *whhSg, *wihS, *whhS, *wfc3, *wfc4;
  u16 *waB, *wbB, *wihQp, *whhQb, *wihSgB, *whhSgB, *wihSp, *whhSb, *wfc3p, *wfc4p;
};

// waB tiled (R9-verified): [t=640][kk=8][lane=64][e=8];
//   (t,kk,l,e) = W2a[t*16+(l&15)][kk*32+(l>>4)*8+e]
// wbB tiled + PERMUTED hidden order (matches k2's paired-u32 bounce):
//   q=(l>>4)*8+e; (s,l,e) = W2b[(l&15)][s*32 + (q&1)*16 + (q>>1)]  (o>=8 -> 0)
__global__ __launch_bounds__(256) void kconv(CVA a){
  int id = blockIdx.x*256 + threadIdx.x;
  if (id < 327680){                    // waB: thread = (t*8+kk)*64 + l, 8 e's
    int g = id >> 6;                   // t*8+kk
    int l = id & 63;
    int col = (g>>3)*16 + (l & 15);
    int k0  = (g&7)*32 + (l >> 4)*8;
    const float* p = a.w2a + (size_t)col*256 + k0;
    f32v4 v0 = *(const f32v4*)p;
    f32v4 v1 = *(const f32v4*)(p+4);
    s16x4 o0, o1;
    #pragma unroll
    for (int e=0;e<4;++e){ o0[e]=(short)f2b(v0[e]); o1[e]=(short)f2b(v1[e]); }
    u16* d = a.waB + (size_t)g*512 + l*8;
    *(s16x4*)d = o0; *(s16x4*)(d+4) = o1;
    return;
  }
  id -= 327680;
  if (id < 20480){                     // wbB: thread = s*64 + l, 8 e's (permuted)
    int l = id & 63;
    int o = l & 15;
    int b = (l >> 4)*4;                // q0>>1
    u16* d = a.wbB + (size_t)id*8;
    if (o < 8){
      int s = id >> 6;
      const float* p = a.w2b + (size_t)o*10240 + s*32;
      f32v4 v0 = *(const f32v4*)(p + b);
      f32v4 v1 = *(const f32v4*)(p + 16 + b);
      s16x4 o0, o1;
      o0[0]=(short)f2b(v0[0]); o0[1]=(short)f2b(v1[0]);
      o0[2]=(short)f2b(v0[1]); o0[3]=(short)f2b(v1[1]);
      o1[0]=(short)f2b(v0[2]); o1[1]=(short)f2b(v1[2]);
      o1[2]=(short)f2b(v0[3]); o1[3]=(short)f2b(v1[3]);
      *(s16x4*)d = o0; *(s16x4*)(d+4) = o1;
    } else {
      *(s16x4*)d = (s16x4){0,0,0,0}; *(s16x4*)(d+4) = (s16x4){0,0,0,0};
    }
    return;
  }
  id -= 20480;
  if (id < 12288){ int j=id>>5, k=id&31; a.wihQp[id] = (k<20)? f2b(a.wihQ[j*20+k]) : (u16)0; return; }
  id -= 12288;
  if (id < 49152){ a.whhQb[id] = f2b(a.whhQ[id]); return; }
  id -= 49152;
  if (id < 49152){ a.wihSgB[id] = f2b(a.wihSg[id]); return; }
  id -= 49152;
  if (id < 49152){ a.whhSgB[id] = f2b(a.whhSg[id]); return; }
  id -= 49152;
  if (id < 12288){ int j=id>>5, k=id&31; a.wihSp[id] = (k<6)? f2b(a.wihS[j*6+k]) : (u16)0; return; }
  id -= 12288;
  if (id < 49152){ a.whhSb[id] = f2b(a.whhS[id]); return; }
  id -= 49152;
  if (id < 2560){ int j=id/160, k=id%160; a.wfc3p[id] = (k<136)? f2b(a.wfc3[j*136+k]) : (u16)0; return; }
  id -= 2560;
  if (id < 20480){ int j=id/160, k=id%160; a.wfc4p[id] = (k<144)? f2b(a.wfc4[j*144+k]) : (u16)0; return; }
}

// ---------------- GRU block step (32 rows, 256 threads = 4 waves) ----------------
template<int KX, int LDX, bool SOUT, bool GB16, bool GF32>
__device__ __forceinline__ void gru_step(
    const u16* sX, const u16* sH,
    const u16* __restrict__ Wih, const int ldwih, const u16* __restrict__ Whh,
    const float* __restrict__ bih, const float* __restrict__ bhh,
    float* __restrict__ gOutF, u16* sOut,
    u16* __restrict__ in2T, int row0, int colOff)
{
  const int tid = threadIdx.x;
  const int w = tid>>6, lane = tid&63, c = lane&15, khi = lane>>4;
  for (int nn=0; nn<2; ++nn){
    const int n = w*2+nn;
    const int j = n*16 + c;
    const float bir=bih[j], biz=bih[128+j], bin=bih[256+j];
    const float bhr=bhh[j], bhz=bhh[128+j], bhn=bhh[256+j];
    bf16x8 BX0[KX], BX1[KX], BX2[KX], BH0[4], BH1[4], BH2[4];
    #pragma unroll
    for (int kk=0;kk<KX;++kk){
      const u16* p = Wih + j*ldwih + kk*32 + khi*8;
      BX0[kk] = *(const bf16x8*)(p);
      BX1[kk] = *(const bf16x8*)(p + 128*ldwih);
      BX2[kk] = *(const bf16x8*)(p + 256*ldwih);
    }
    #pragma unroll
    for (int kk=0;kk<4;++kk){
      const u16* p = Whh + j*128 + kk*32 + khi*8;
      BH0[kk] = *(const bf16x8*)(p);
      BH1[kk] = *(const bf16x8*)(p + 128*128);
      BH2[kk] = *(const bf16x8*)(p + 256*128);
    }
    #pragma unroll
    for (int m=0;m<2;++m){
      f32x4 ir={0,0,0,0}, iz={0,0,0,0}, inx={0,0,0,0};
      f32x4 hr={0,0,0,0}, hz={0,0,0,0}, hn={0,0,0,0};
      #pragma unroll
      for (int kk=0;kk<KX;++kk){
        bf16x8 A = *(const bf16x8*)(sX + (m*16+c)*LDX + kk*32 + khi*8);
        ir  = mfma16(A, BX0[kk], ir);
        iz  = mfma16(A, BX1[kk], iz);
        inx = mfma16(A, BX2[kk], inx);
      }
      #pragma unroll
      for (int kk=0;kk<4;++kk){
        bf16x8 A = *(const bf16x8*)(sH + (m*16+c)*136 + kk*32 + khi*8);
        hr = mfma16(A, BH0[kk], hr);
        hz = mfma16(A, BH1[kk], hz);
        hn = mfma16(A, BH2[kk], hn);
      }
      #pragma unroll
      for (int e=0;e<4;++e){
        int r = m*16 + khi*4 + e;
        float rg = sigm(ir[e]+hr[e]+bir+bhr);
        float zg = sigm(iz[e]+hz[e]+biz+bhz);
        float ng = tanhfast(inx[e]+bin + rg*(hn[e]+bhn));
        float hold = b2f(sH[r*136 + j]);
        float hv = (1.f-zg)*ng + zg*hold;
        if (GF32) gOutF[r*128 + j] = hv;
        if (SOUT) sOut[r*136 + j] = f2b(hv);
        if (GB16) in2t_store(in2T, row0 + r, colOff + j, f2b(hv));
      }
    }
  }
}

// ---------------- K1: chain up to in2T ----------------
struct K1A {
  const float *y,*u,*m1x,*hQ,*hSg,*hS,*F,*G,*Hm,*W5,*b5,
              *bihQ,*bhhQ,*bihSg,*bhhSg,*W1,*b1,*W7,*b7,*bihS,*bhhS;
  const u16 *wihQp,*whhQ,*wihSg,*whhSg,*wihSp,*whhS;
  float *outHQ,*outHS,*xp,*dy;
  u16 *in2T;
};

__device__ __forceinline__ void load_h_tile(u16* dst, const float* src, int row0){
  const int tid = threadIdx.x;
  #pragma unroll
  for (int i=0;i<4;++i){
    int f4 = tid + i*256;
    int r = f4>>5, c4 = f4&31;
    f32v4 v = *(const f32v4*)(src + (row0+r)*128 + c4*4);
    s16x4 o;
    o[0]=(short)f2b(v[0]); o[1]=(short)f2b(v[1]);
    o[2]=(short)f2b(v[2]); o[3]=(short)f2b(v[3]);
    *(s16x4*)(dst + r*136 + c4*4) = o;
  }
}

__global__ __launch_bounds__(256) void k1(K1A a){
  __shared__ u16 sX[32*40];
  __shared__ u16 sH[32*136];
  __shared__ u16 sXL[32*136];
  __shared__ u16 sSig[32*136];
  __shared__ float sDY[64];
  const int row0 = blockIdx.x*32;
  const int tid = threadIdx.x;
  const int wid = tid>>6, lane = tid&63, c = lane&15, khi = lane>>4;

  load_h_tile(sH, a.hQ, row0);
  if (tid < 32){
    int r = tid, row = row0 + r;
    float xpost[4], uu[2], xpr[4];
    #pragma unroll
    for (int i=0;i<4;++i) xpost[i]=a.m1x[row*4+i];
    uu[0]=a.u[row*2]; uu[1]=a.u[row*2+1];
    #pragma unroll
    for (int i=0;i<4;++i){
      float s=0.f;
      #pragma unroll
      for (int jj=0;jj<4;++jj) s += a.F[i*4+jj]*xpost[jj];
      #pragma unroll
      for (int jj=0;jj<2;++jj) s += a.G[i*2+jj]*uu[jj];
      xpr[i]=s; a.xp[row*4+i]=s;
    }
    #pragma unroll
    for (int nn2=0;nn2<2;++nn2){
      float s=0.f;
      #pragma unroll
      for (int jj=0;jj<4;++jj) s += a.Hm[nn2*4+jj]*xpr[jj];
      float d = a.y[row*2+nn2]-s;
      a.dy[row*2+nn2]=d; sDY[r*2+nn2]=d;
    }
    #pragma unroll
    for (int o=0;o<20;++o){
      float s=a.b5[o];
      #pragma unroll
      for (int k=0;k<4;++k) s += a.W5[o*4+k]*xpr[k];
      sX[r*40+o]=f2b(fmaxf(s,0.f));
    }
    for (int o=20;o<40;++o) sX[r*40+o]=0;
  }
  __syncthreads();
  gru_step<1,40,true,false,true>(sX, sH, a.wihQp, 32, a.whhQ, a.bihQ, a.bhhQ,
                                 a.outHQ + row0*128, sXL, nullptr, 0, 0);
  __syncthreads();
  load_h_tile(sH, a.hSg, row0);
  __syncthreads();
  gru_step<4,136,true,true,false>(sXL, sH, a.wihSg, 128, a.whhSg, a.bihSg, a.bhhSg,
                                  nullptr, sSig, a.in2T, row0, 0);
  __syncthreads();
  // fc1 via MFMA on wave 0; fc7 on wave 1; pad-zero on waves 2-3 (concurrent)
  if (wid == 0){
    bf16x8 Bf[4];
    #pragma unroll
    for (int kk=0;kk<4;++kk){
      bf16x8 b = (bf16x8){0,0,0,0,0,0,0,0};
      if (c < 4){
        const float* p = a.W1 + c*128 + kk*32 + khi*8;
        f32v4 v0 = *(const f32v4*)p;
        f32v4 v1 = *(const f32v4*)(p+4);
        #pragma unroll
        for (int e=0;e<4;++e){ b[e]=(short)f2b(v0[e]); b[4+e]=(short)f2b(v1[e]); }
      }
      Bf[kk] = b;
    }
    float bj = (c < 4) ? a.b1[c] : 0.f;
    #pragma unroll
    for (int m=0;m<2;++m){
      f32x4 C = {0,0,0,0};
      #pragma unroll
      for (int kk=0;kk<4;++kk){
        bf16x8 A = *(const bf16x8*)(sSig + (m*16+c)*136 + kk*32 + khi*8);
        C = mfma16(A, Bf[kk], C);
      }
      if (c < 4){
        #pragma unroll
        for (int e=0;e<4;++e){
          int r = m*16 + khi*4 + e;
          sX[r*40 + c] = f2b(fmaxf(C[e]+bj, 0.f));
        }
      }
    }
  } else if (wid == 1){
    int r = lane>>1, o = lane&1;
    float s = a.b7[o] + a.W7[o*2]*sDY[r*2] + a.W7[o*2+1]*sDY[r*2+1];
    sX[r*40+4+o] = f2b(fmaxf(s,0.f));
  } else {
    for (int i=tid-128;i<832;i+=128){ int r=i/26, cc=6+(i%26); sX[r*40+cc]=0; }
  }
  load_h_tile(sH, a.hS, row0);
  __syncthreads();
  gru_step<1,40,false,true,true>(sX, sH, a.wihSp, 32, a.whhS, a.bihS, a.bhhS,
                                 a.outHS + row0*128, nullptr, a.in2T, row0, 128);
}

// ---------------- K2: fused fc2a -> relu -> fc2b (R13, unchanged) -------------
struct K2A {
  const u16 *waB, *wbB, *in2T;
  const float *b2a;
  float *parts;     // [8][8192][8] f32
};

__global__ __launch_bounds__(512) void k2(K2A a){
  __shared__ u16 sA[128*256];          // 64KB: [rt=8][kk=8][512]
  __shared__ u16 sHw[8][16*40];        // 10KB per-wave slab bounce
  const int bid = blockIdx.x;
  const int rb = bid>>3, ch = bid&7;
  const int tid = threadIdx.x;
  const int wid = tid>>6, lane = tid&63, c = lane&15, khi = lane>>4;
  const int wr = wid>>2, wc = wid&3;   // 2 row-bands x 4 col-bands

  {
    const s16x4* src = (const s16x4*)(a.in2T + (size_t)rb*32768);
    s16x4* dst = (s16x4*)sA;
    #pragma unroll
    for (int i=0;i<16;++i) dst[tid + i*512] = src[tid + i*512];
  }
  __syncthreads();

  f32x4 C2[4];
  #pragma unroll
  for (int m=0;m<4;++m) C2[m] = (f32x4){0,0,0,0};
  u16* hw = &sHw[wid][0];

  for (int it=0; it<10; ++it){
    const int colb = ch*1280 + it*128 + wc*32;   // wave's 32 cols
    const int t0 = colb>>4;
    f32x4 C1[4][2];
    #pragma unroll
    for (int m=0;m<4;++m){ C1[m][0]=(f32x4){0,0,0,0}; C1[m][1]=(f32x4){0,0,0,0}; }
    #pragma unroll
    for (int kk=0;kk<8;++kk){
      bf16x8 Bf0 = *(const bf16x8*)(a.waB + (size_t)(t0*8+kk)*512 + lane*8);
      bf16x8 Bf1 = *(const bf16x8*)(a.waB + (size_t)((t0+1)*8+kk)*512 + lane*8);
      #pragma unroll
      for (int m=0;m<4;++m){
        bf16x8 Ar = *(const bf16x8*)(sA + (size_t)((wr*4+m)*8+kk)*512 + lane*8);
        C1[m][0] = mfma16(Ar, Bf0, C1[m][0]);
        C1[m][1] = mfma16(Ar, Bf1, C1[m][1]);
      }
    }
    bf16x8 B2 = *(const bf16x8*)(a.wbB + (size_t)(colb>>5)*512 + lane*8);
    const float bias0 = a.b2a[colb + c];
    const float bias1 = a.b2a[colb + 16 + c];
    #pragma unroll
    for (int m=0;m<4;++m){
      #pragma unroll
      for (int e=0;e<4;++e){
        float v0 = fmaxf(C1[m][0][e]+bias0, 0.f);
        float v1 = fmaxf(C1[m][1][e]+bias1, 0.f);
        u32 w = (u32)f2b(v0) | ((u32)f2b(v1)<<16);
        *(u32*)(hw + (khi*4+e)*40 + 2*c) = w;
      }
      bf16x8 A2 = *(const bf16x8*)(hw + c*40 + khi*8);
      C2[m] = mfma16(A2, B2, C2[m]);
    }
  }
  __syncthreads();
  float* sRed = (float*)sA;
  if (c < 8){
    #pragma unroll
    for (int m=0;m<4;++m)
      #pragma unroll
      for (int e=0;e<4;++e)
        sRed[wid*512 + (m*16+khi*4+e)*8 + c] = C2[m][e];
  }
  __syncthreads();
  #pragma unroll
  for (int i=tid;i<1024;i+=512){
    int r=i>>3, o=i&7;
    int band=r>>6, rl=r&63;
    float s=0.f;
    #pragma unroll
    for (int w2=0;w2<4;++w2) s += sRed[(band*4+w2)*512 + rl*8 + o];
    a.parts[(size_t)ch*65536 + (size_t)(rb*128+r)*8 + o] = s;
  }
}

// ---------------- K3: out2 from parts, fc3, fc4, posterior (32 rows/block) ----
struct K3A {
  const float *parts;
  const float *b2b, *bfc3, *bfc4, *xp, *dy, *innov;
  const u16 *in2T, *wfc3p, *wfc4p;
  float *outPost, *outHSig;
};

__global__ __launch_bounds__(256) void k3(K3A a){
  __shared__ u16 sA[32*168];
  __shared__ u16 sX4[32*168];
  __shared__ float sOut2[32*8];
  const int row0 = blockIdx.x*32;
  const int tid = threadIdx.x;
  {
    int r=tid>>3, o=tid&7, row=row0+r;
    float s = a.b2b[o];
    #pragma unroll
    for (int chv=0;chv<8;++chv) s += a.parts[chv*65536 + row*8 + o];
    sOut2[tid]=s;
    sA[r*168+128+o]=f2b(s);
  }
  for (int i=tid;i<1024;i+=256){
    int r=i>>5, c4=i&31;
    int row = row0 + r, col = c4*4;
    *(s16x4*)(sX4 + r*168 + col) = in2t_load4(a.in2T, row, col);         // hSig
    *(s16x4*)(sA  + r*168 + col) = in2t_load4(a.in2T, row, 128 + col);   // hS_new
  }
  if (tid < 192){ int r=tid/6, c4=tid%6; *(s16x4*)(sA + r*168 + 136 + c4*4) = (s16x4){0,0,0,0}; }
  if (tid < 128){ int r=tid>>2, c4=tid&3; *(s16x4*)(sX4 + r*168 + 144 + c4*4) = (s16x4){0,0,0,0}; }
  __syncthreads();
  if (tid < 128){
    int r = tid>>2, m = tid&3, row = row0+r;
    float g = 1.f/(1.f+__expf(-a.innov[0]));
    float d0 = a.dy[row*2], d1 = a.dy[row*2+1];
    float k0 = sOut2[r*8+m*2], k1 = sOut2[r*8+m*2+1];
    a.outPost[row*4+m] = a.xp[row*4+m] + g*(k0*d0+k1*d1);
  }
  const int w = tid>>6, lane = tid&63, c = lane&15, khi = lane>>4;
  if (w < 2){
    f32x4 C3 = {0,0,0,0};
    #pragma unroll
    for (int kk=0;kk<5;++kk){
      bf16x8 A  = *(const bf16x8*)(sA + (w*16+c)*168 + kk*32 + khi*8);
      bf16x8 Bf = *(const bf16x8*)(a.wfc3p + c*160 + kk*32 + khi*8);
      C3 = mfma16(A,Bf,C3);
    }
    float bj = a.bfc3[c];
    #pragma unroll
    for (int e=0;e<4;++e){
      int r = w*16 + khi*4 + e;
      sX4[r*168 + 128 + c] = f2b(fmaxf(C3[e]+bj, 0.f));
    }
  }
  __syncthreads();
  for (int nn=0;nn<2;++nn){
    int j = (w*2+nn)*16 + c;
    bf16x8 Bf[5];
    #pragma unroll
    for (int kk=0;kk<5;++kk) Bf[kk] = *(const bf16x8*)(a.wfc4p + j*160 + kk*32 + khi*8);
    float bj = a.bfc4[j];
    #pragma unroll
    for (int m=0;m<2;++m){
      f32x4 C = {0,0,0,0};
      #pragma unroll
      for (int kk=0;kk<5;++kk){
        bf16x8 A = *(const bf16x8*)(sX4 + (m*16+c)*168 + kk*32 + khi*8);
        C = mfma16(A, Bf[kk], C);
      }
      #pragma unroll
      for (int e=0;e<4;++e){
        int r = m*16 + khi*4 + e;
        a.outHSig[(row0+r)*128 + j] = fmaxf(C[e]+bj, 0.f);
      }
    }
  }
}

// ---------------- launcher ----------------
extern "C" void kernel_launch(void* const* d_in, const int* in_sizes, int n_in,
                              void* d_out, int out_size, void* d_ws, size_t ws_size,
                              hipStream_t stream){
  const float* y    = (const float*)d_in[0];
  const float* u    = (const float*)d_in[1];
  const float* m1x  = (const float*)d_in[2];
  const float* hQ   = (const float*)d_in[3];
  const float* hSg  = (const float*)d_in[4];
  const float* hS   = (const float*)d_in[5];
  const float* F    = (const float*)d_in[6];
  const float* G    = (const float*)d_in[7];
  const float* Hm   = (const float*)d_in[8];
  const float* innov= (const float*)d_in[9];
  const float* W5   = (const float*)d_in[10];
  const float* b5   = (const float*)d_in[11];
  const float* WihQ = (const float*)d_in[12];
  const float* WhhQ = (const float*)d_in[13];
  const float* bihQ = (const float*)d_in[14];
  const float* bhhQ = (const float*)d_in[15];
  const float* WihSg= (const float*)d_in[16];
  const float* WhhSg= (const float*)d_in[17];
  const float* bihSg= (const float*)d_in[18];
  const float* bhhSg= (const float*)d_in[19];
  const float* W1   = (const float*)d_in[20];
  const float* b1   = (const float*)d_in[21];
  const float* W7   = (const float*)d_in[22];
  const float* b7   = (const float*)d_in[23];
  const float* WihS = (const float*)d_in[24];
  const float* WhhS = (const float*)d_in[25];
  const float* bihS = (const float*)d_in[26];
  const float* bhhS = (const float*)d_in[27];
  const float* W2a  = (const float*)d_in[28];
  const float* b2a  = (const float*)d_in[29];
  const float* W2b  = (const float*)d_in[30];
  const float* b2b  = (const float*)d_in[31];
  const float* W3   = (const float*)d_in[32];
  const float* b3   = (const float*)d_in[33];
  const float* W4   = (const float*)d_in[34];
  const float* b4   = (const float*)d_in[35];

  const size_t WS_NEEDED = 12547072;
  if (ws_size < WS_NEEDED) return;

  char* ws = (char*)d_ws;
  u16*  waB   = (u16*)(ws + 0);
  u16*  wbB   = (u16*)(ws + 5242880);
  u16*  in2T  = (u16*)(ws + 5570560);
  float* parts= (float*)(ws + 9764864);     // 8*65536*4B = 2MB
  float* xp   = (float*)(ws + 11862016);
  float* dyb  = (float*)(ws + 11993088);
  u16* wihQp  = (u16*)(ws + 12058624);
  u16* whhQb  = (u16*)(ws + 12083200);
  u16* wihSgB = (u16*)(ws + 12181504);
  u16* whhSgB = (u16*)(ws + 12279808);
  u16* wihSp  = (u16*)(ws + 12378112);
  u16* whhSb  = (u16*)(ws + 12402688);
  u16* wfc3p  = (u16*)(ws + 12500992);
  u16* wfc4p  = (u16*)(ws + 12506112);

  float* outF    = (float*)d_out;
  float* outPost = outF;
  float* outHQ   = outF + 32768;
  float* outHSig = outF + 32768 + 1048576;
  float* outHS   = outF + 32768 + 2*1048576;

  CVA cv{W2a, W2b, WihQ, WhhQ, WihSg, WhhSg, WihS, WhhS, W3, W4,
         waB, wbB, wihQp, whhQb, wihSgB, whhSgB, wihSp, whhSb, wfc3p, wfc4p};
  kconv<<<dim3(2314), dim3(256), 0, stream>>>(cv);

  K1A a1{y,u,m1x,hQ,hSg,hS,F,G,Hm,W5,b5,bihQ,bhhQ,bihSg,bhhSg,W1,b1,W7,b7,bihS,bhhS,
         wihQp,whhQb,wihSgB,whhSgB,wihSp,whhSb,
         outHQ,outHS,xp,dyb,in2T};
  k1<<<dim3(256), dim3(256), 0, stream>>>(a1);

  K2A a2{waB, wbB, in2T, b2a, parts};
  k2<<<dim3(512), dim3(512), 0, stream>>>(a2);

  K3A a3{parts, b2b, b3, b4, xp, dyb, innov, in2T, wfc3p, wfc4p, outPost, outHSig};
  k3<<<dim3(256), dim3(256), 0, stream>>>(a3);
}

// Round 15
// 91.067 us; speedup vs baseline: 1.6489x; 1.0214x over previous
//
#include <hip/hip_runtime.h>
#include <hip/hip_bf16.h>

typedef __attribute__((ext_vector_type(8))) short bf16x8;
typedef __attribute__((ext_vector_type(4))) float f32x4;
typedef __attribute__((ext_vector_type(4))) short s16x4;
typedef __attribute__((ext_vector_type(4))) float f32v4;
typedef unsigned short u16;
typedef unsigned int u32;

__device__ inline u16 f2b(float f){ __hip_bfloat16 b = __float2bfloat16(f); return __builtin_bit_cast(unsigned short, b); }
__device__ inline float b2f(u16 u){ unsigned int x = ((unsigned int)u)<<16; return __builtin_bit_cast(float, x); }
__device__ inline float sigm(float x){ return 1.f/(1.f+__expf(-x)); }
__device__ inline float tanhfast(float x){ float e = __expf(2.f*x); return 1.f - 2.f/(e+1.f); }

__device__ inline f32x4 mfma16(bf16x8 a, bf16x8 b, f32x4 c){
  return __builtin_amdgcn_mfma_f32_16x16x32_bf16(a, b, c, 0, 0, 0);
}

// in2T fragment-tiled (R9-verified): element (row, col) at
//   ((row>>4)*8 + (col>>5))*512 + (((col>>3)&3)*16 + (row&15))*8 + (col&7)
__device__ __forceinline__ void in2t_store(u16* t, int row, int col, u16 v){
  int rt = row>>4, kk = col>>5, khi = (col>>3)&3, e = col&7;
  t[(size_t)(rt*8+kk)*512 + (khi*16 + (row&15))*8 + e] = v;
}
__device__ __forceinline__ s16x4 in2t_load4(const u16* t, int row, int col){
  int rt = row>>4, kk = col>>5, khi = (col>>3)&3, e = col&7;   // col 4-aligned
  return *(const s16x4*)(t + (size_t)(rt*8+kk)*512 + (khi*16 + (row&15))*8 + e);
}

// ---------------- weight conversion (coalesced, 8 elem/thread for big arrays) --
struct CVA {
  const float *w2a, *w2b, *wihQ, *whhQ, *wihSg, *whhSg, *wihS, *whhS, *wfc3, *wfc4;
  u16 *waB, *wbB, *wihQp, *whhQb, *wihSgB, *whhSgB, *wihSp, *whhSb, *wfc3p, *wfc4p;
};

// waB tiled (R9-verified): [t=640][kk=8][lane=64][e=8];
//   (t,kk,l,e) = W2a[t*16+(l&15)][kk*32+(l>>4)*8+e]
// wbB tiled + PERMUTED hidden order (matches k2's paired-u32 bounce):
//   q=(l>>4)*8+e; (s,l,e) = W2b[(l&15)][s*32 + (q&1)*16 + (q>>1)]  (o>=8 -> 0)
__global__ __launch_bounds__(256) void kconv(CVA a){
  int id = blockIdx.x*256 + threadIdx.x;
  if (id < 327680){                    // waB: thread = (t*8+kk)*64 + l, 8 e's
    int g = id >> 6;                   // t*8+kk
    int l = id & 63;
    int col = (g>>3)*16 + (l & 15);
    int k0  = (g&7)*32 + (l >> 4)*8;
    const float* p = a.w2a + (size_t)col*256 + k0;
    f32v4 v0 = *(const f32v4*)p;
    f32v4 v1 = *(const f32v4*)(p+4);
    s16x4 o0, o1;
    #pragma unroll
    for (int e=0;e<4;++e){ o0[e]=(short)f2b(v0[e]); o1[e]=(short)f2b(v1[e]); }
    u16* d = a.waB + (size_t)g*512 + l*8;
    *(s16x4*)d = o0; *(s16x4*)(d+4) = o1;
    return;
  }
  id -= 327680;
  if (id < 20480){                     // wbB: thread = s*64 + l, 8 e's (permuted)
    int l = id & 63;
    int o = l & 15;
    int b = (l >> 4)*4;                // q0>>1
    u16* d = a.wbB + (size_t)id*8;
    if (o < 8){
      int s = id >> 6;
      const float* p = a.w2b + (size_t)o*10240 + s*32;
      f32v4 v0 = *(const f32v4*)(p + b);
      f32v4 v1 = *(const f32v4*)(p + 16 + b);
      s16x4 o0, o1;
      o0[0]=(short)f2b(v0[0]); o0[1]=(short)f2b(v1[0]);
      o0[2]=(short)f2b(v0[1]); o0[3]=(short)f2b(v1[1]);
      o1[0]=(short)f2b(v0[2]); o1[1]=(short)f2b(v1[2]);
      o1[2]=(short)f2b(v0[3]); o1[3]=(short)f2b(v1[3]);
      *(s16x4*)d = o0; *(s16x4*)(d+4) = o1;
    } else {
      *(s16x4*)d = (s16x4){0,0,0,0}; *(s16x4*)(d+4) = (s16x4){0,0,0,0};
    }
    return;
  }
  id -= 20480;
  if (id < 12288){ int j=id>>5, k=id&31; a.wihQp[id] = (k<20)? f2b(a.wihQ[j*20+k]) : (u16)0; return; }
  id -= 12288;
  if (id < 49152){ a.whhQb[id] = f2b(a.whhQ[id]); return; }
  id -= 49152;
  if (id < 49152){ a.wihSgB[id] = f2b(a.wihSg[id]); return; }
  id -= 49152;
  if (id < 49152){ a.whhSgB[id] = f2b(a.whhSg[id]); return; }
  id -= 49152;
  if (id < 12288){ int j=id>>5, k=id&31; a.wihSp[id] = (k<6)? f2b(a.wihS[j*6+k]) : (u16)0; return; }
  id -= 12288;
  if (id < 49152){ a.whhSb[id] = f2b(a.whhS[id]); return; }
  id -= 49152;
  if (id < 2560){ int j=id/160, k=id%160; a.wfc3p[id] = (k<136)? f2b(a.wfc3[j*136+k]) : (u16)0; return; }
  id -= 2560;
  if (id < 20480){ int j=id/160, k=id%160; a.wfc4p[id] = (k<144)? f2b(a.wfc4[j*144+k]) : (u16)0; return; }
}

// ---------------- GRU block step (32 rows, 256 threads = 4 waves) ----------------
template<int KX, int LDX, bool SOUT, bool GB16, bool GF32>
__device__ __forceinline__ void gru_step(
    const u16* sX, const u16* sH,
    const u16* __restrict__ Wih, const int ldwih, const u16* __restrict__ Whh,
    const float* __restrict__ bih, const float* __restrict__ bhh,
    float* __restrict__ gOutF, u16* sOut,
    u16* __restrict__ in2T, int row0, int colOff)
{
  const int tid = threadIdx.x;
  const int w = tid>>6, lane = tid&63, c = lane&15, khi = lane>>4;
  for (int nn=0; nn<2; ++nn){
    const int n = w*2+nn;
    const int j = n*16 + c;
    const float bir=bih[j], biz=bih[128+j], bin=bih[256+j];
    const float bhr=bhh[j], bhz=bhh[128+j], bhn=bhh[256+j];
    bf16x8 BX0[KX], BX1[KX], BX2[KX], BH0[4], BH1[4], BH2[4];
    #pragma unroll
    for (int kk=0;kk<KX;++kk){
      const u16* p = Wih + j*ldwih + kk*32 + khi*8;
      BX0[kk] = *(const bf16x8*)(p);
      BX1[kk] = *(const bf16x8*)(p + 128*ldwih);
      BX2[kk] = *(const bf16x8*)(p + 256*ldwih);
    }
    #pragma unroll
    for (int kk=0;kk<4;++kk){
      const u16* p = Whh + j*128 + kk*32 + khi*8;
      BH0[kk] = *(const bf16x8*)(p);
      BH1[kk] = *(const bf16x8*)(p + 128*128);
      BH2[kk] = *(const bf16x8*)(p + 256*128);
    }
    #pragma unroll
    for (int m=0;m<2;++m){
      f32x4 ir={0,0,0,0}, iz={0,0,0,0}, inx={0,0,0,0};
      f32x4 hr={0,0,0,0}, hz={0,0,0,0}, hn={0,0,0,0};
      #pragma unroll
      for (int kk=0;kk<KX;++kk){
        bf16x8 A = *(const bf16x8*)(sX + (m*16+c)*LDX + kk*32 + khi*8);
        ir  = mfma16(A, BX0[kk], ir);
        iz  = mfma16(A, BX1[kk], iz);
        inx = mfma16(A, BX2[kk], inx);
      }
      #pragma unroll
      for (int kk=0;kk<4;++kk){
        bf16x8 A = *(const bf16x8*)(sH + (m*16+c)*136 + kk*32 + khi*8);
        hr = mfma16(A, BH0[kk], hr);
        hz = mfma16(A, BH1[kk], hz);
        hn = mfma16(A, BH2[kk], hn);
      }
      #pragma unroll
      for (int e=0;e<4;++e){
        int r = m*16 + khi*4 + e;
        float rg = sigm(ir[e]+hr[e]+bir+bhr);
        float zg = sigm(iz[e]+hz[e]+biz+bhz);
        float ng = tanhfast(inx[e]+bin + rg*(hn[e]+bhn));
        float hold = b2f(sH[r*136 + j]);
        float hv = (1.f-zg)*ng + zg*hold;
        if (GF32) gOutF[r*128 + j] = hv;
        if (SOUT) sOut[r*136 + j] = f2b(hv);
        if (GB16) in2t_store(in2T, row0 + r, colOff + j, f2b(hv));
      }
    }
  }
}

// ---------------- K1: chain up to in2T ----------------
struct K1A {
  const float *y,*u,*m1x,*hQ,*hSg,*hS,*F,*G,*Hm,*W5,*b5,
              *bihQ,*bhhQ,*bihSg,*bhhSg,*W1,*b1,*W7,*b7,*bihS,*bhhS;
  const u16 *wihQp,*whhQ,*wihSg,*whhSg,*wihSp,*whhS;
  float *outHQ,*outHS,*xp,*dy;
  u16 *in2T;
};

__device__ __forceinline__ void load_h_tile(u16* dst, const float* src, int row0){
  const int tid = threadIdx.x;
  #pragma unroll
  for (int i=0;i<4;++i){
    int f4 = tid + i*256;
    int r = f4>>5, c4 = f4&31;
    f32v4 v = *(const f32v4*)(src + (row0+r)*128 + c4*4);
    s16x4 o;
    o[0]=(short)f2b(v[0]); o[1]=(short)f2b(v[1]);
    o[2]=(short)f2b(v[2]); o[3]=(short)f2b(v[3]);
    *(s16x4*)(dst + r*136 + c4*4) = o;
  }
}

__global__ __launch_bounds__(256) void k1(K1A a){
  __shared__ u16 sX[32*40];
  __shared__ u16 sH[32*136];
  __shared__ u16 sXL[32*136];
  __shared__ u16 sSig[32*136];
  __shared__ float sDY[64];
  const int row0 = blockIdx.x*32;
  const int tid = threadIdx.x;
  const int wid = tid>>6, lane = tid&63, c = lane&15, khi = lane>>4;

  load_h_tile(sH, a.hQ, row0);
  if (tid < 32){
    int r = tid, row = row0 + r;
    float xpost[4], uu[2], xpr[4];
    #pragma unroll
    for (int i=0;i<4;++i) xpost[i]=a.m1x[row*4+i];
    uu[0]=a.u[row*2]; uu[1]=a.u[row*2+1];
    #pragma unroll
    for (int i=0;i<4;++i){
      float s=0.f;
      #pragma unroll
      for (int jj=0;jj<4;++jj) s += a.F[i*4+jj]*xpost[jj];
      #pragma unroll
      for (int jj=0;jj<2;++jj) s += a.G[i*2+jj]*uu[jj];
      xpr[i]=s; a.xp[row*4+i]=s;
    }
    #pragma unroll
    for (int nn2=0;nn2<2;++nn2){
      float s=0.f;
      #pragma unroll
      for (int jj=0;jj<4;++jj) s += a.Hm[nn2*4+jj]*xpr[jj];
      float d = a.y[row*2+nn2]-s;
      a.dy[row*2+nn2]=d; sDY[r*2+nn2]=d;
    }
    #pragma unroll
    for (int o=0;o<20;++o){
      float s=a.b5[o];
      #pragma unroll
      for (int k=0;k<4;++k) s += a.W5[o*4+k]*xpr[k];
      sX[r*40+o]=f2b(fmaxf(s,0.f));
    }
    for (int o=20;o<40;++o) sX[r*40+o]=0;
  }
  __syncthreads();
  gru_step<1,40,true,false,true>(sX, sH, a.wihQp, 32, a.whhQ, a.bihQ, a.bhhQ,
                                 a.outHQ + row0*128, sXL, nullptr, 0, 0);
  __syncthreads();
  load_h_tile(sH, a.hSg, row0);
  __syncthreads();
  gru_step<4,136,true,true,false>(sXL, sH, a.wihSg, 128, a.whhSg, a.bihSg, a.bhhSg,
                                  nullptr, sSig, a.in2T, row0, 0);
  __syncthreads();
  // fc1 via MFMA on wave 0; fc7 on wave 1; pad-zero on waves 2-3 (concurrent)
  if (wid == 0){
    bf16x8 Bf[4];
    #pragma unroll
    for (int kk=0;kk<4;++kk){
      bf16x8 b = (bf16x8){0,0,0,0,0,0,0,0};
      if (c < 4){
        const float* p = a.W1 + c*128 + kk*32 + khi*8;
        f32v4 v0 = *(const f32v4*)p;
        f32v4 v1 = *(const f32v4*)(p+4);
        #pragma unroll
        for (int e=0;e<4;++e){ b[e]=(short)f2b(v0[e]); b[4+e]=(short)f2b(v1[e]); }
      }
      Bf[kk] = b;
    }
    float bj = (c < 4) ? a.b1[c] : 0.f;
    #pragma unroll
    for (int m=0;m<2;++m){
      f32x4 C = {0,0,0,0};
      #pragma unroll
      for (int kk=0;kk<4;++kk){
        bf16x8 A = *(const bf16x8*)(sSig + (m*16+c)*136 + kk*32 + khi*8);
        C = mfma16(A, Bf[kk], C);
      }
      if (c < 4){
        #pragma unroll
        for (int e=0;e<4;++e){
          int r = m*16 + khi*4 + e;
          sX[r*40 + c] = f2b(fmaxf(C[e]+bj, 0.f));
        }
      }
    }
  } else if (wid == 1){
    int r = lane>>1, o = lane&1;
    float s = a.b7[o] + a.W7[o*2]*sDY[r*2] + a.W7[o*2+1]*sDY[r*2+1];
    sX[r*40+4+o] = f2b(fmaxf(s,0.f));
  } else {
    for (int i=tid-128;i<832;i+=128){ int r=i/26, cc=6+(i%26); sX[r*40+cc]=0; }
  }
  load_h_tile(sH, a.hS, row0);
  __syncthreads();
  gru_step<1,40,false,true,true>(sX, sH, a.wihSp, 32, a.whhS, a.bihS, a.bhhS,
                                 a.outHS + row0*128, nullptr, a.in2T, row0, 128);
}

// ---------------- K2: fused fc2a -> relu -> fc2b (R13 + latency cuts) ---------
// Changes vs R13: (1) stage-2 operands (B2, bias0/1) hoisted ABOVE the stage-1
// kk loop — their ~300cy L2 latency now hides under the MFMA cluster instead of
// stalling the epilogue each iteration; (2) s_setprio(1) around the stage-1
// MFMA cluster (waves drift with no barriers -> attn-like phase diversity, T5).
struct K2A {
  const u16 *waB, *wbB, *in2T;
  const float *b2a;
  float *parts;     // [8][8192][8] f32
};

__global__ __launch_bounds__(512) void k2(K2A a){
  __shared__ u16 sA[128*256];          // 64KB: [rt=8][kk=8][512]
  __shared__ u16 sHw[8][16*40];        // 10KB per-wave slab bounce
  const int bid = blockIdx.x;
  const int rb = bid>>3, ch = bid&7;
  const int tid = threadIdx.x;
  const int wid = tid>>6, lane = tid&63, c = lane&15, khi = lane>>4;
  const int wr = wid>>2, wc = wid&3;   // 2 row-bands x 4 col-bands

  {
    const s16x4* src = (const s16x4*)(a.in2T + (size_t)rb*32768);
    s16x4* dst = (s16x4*)sA;
    #pragma unroll
    for (int i=0;i<16;++i) dst[tid + i*512] = src[tid + i*512];
  }
  __syncthreads();

  f32x4 C2[4];
  #pragma unroll
  for (int m=0;m<4;++m) C2[m] = (f32x4){0,0,0,0};
  u16* hw = &sHw[wid][0];

  for (int it=0; it<10; ++it){
    const int colb = ch*1280 + it*128 + wc*32;   // wave's 32 cols
    const int t0 = colb>>4;
    // hoisted stage-2 operands: latency hides under the stage-1 MFMA cluster
    bf16x8 B2 = *(const bf16x8*)(a.wbB + (size_t)(colb>>5)*512 + lane*8);
    const float bias0 = a.b2a[colb + c];
    const float bias1 = a.b2a[colb + 16 + c];
    f32x4 C1[4][2];
    #pragma unroll
    for (int m=0;m<4;++m){ C1[m][0]=(f32x4){0,0,0,0}; C1[m][1]=(f32x4){0,0,0,0}; }
    __builtin_amdgcn_s_setprio(1);
    #pragma unroll
    for (int kk=0;kk<8;++kk){
      bf16x8 Bf0 = *(const bf16x8*)(a.waB + (size_t)(t0*8+kk)*512 + lane*8);
      bf16x8 Bf1 = *(const bf16x8*)(a.waB + (size_t)((t0+1)*8+kk)*512 + lane*8);
      #pragma unroll
      for (int m=0;m<4;++m){
        bf16x8 Ar = *(const bf16x8*)(sA + (size_t)((wr*4+m)*8+kk)*512 + lane*8);
        C1[m][0] = mfma16(Ar, Bf0, C1[m][0]);
        C1[m][1] = mfma16(Ar, Bf1, C1[m][1]);
      }
    }
    __builtin_amdgcn_s_setprio(0);
    #pragma unroll
    for (int m=0;m<4;++m){
      #pragma unroll
      for (int e=0;e<4;++e){
        float v0 = fmaxf(C1[m][0][e]+bias0, 0.f);
        float v1 = fmaxf(C1[m][1][e]+bias1, 0.f);
        u32 w = (u32)f2b(v0) | ((u32)f2b(v1)<<16);
        *(u32*)(hw + (khi*4+e)*40 + 2*c) = w;
      }
      bf16x8 A2 = *(const bf16x8*)(hw + c*40 + khi*8);
      C2[m] = mfma16(A2, B2, C2[m]);
    }
  }
  __syncthreads();
  float* sRed = (float*)sA;
  if (c < 8){
    #pragma unroll
    for (int m=0;m<4;++m)
      #pragma unroll
      for (int e=0;e<4;++e)
        sRed[wid*512 + (m*16+khi*4+e)*8 + c] = C2[m][e];
  }
  __syncthreads();
  #pragma unroll
  for (int i=tid;i<1024;i+=512){
    int r=i>>3, o=i&7;
    int band=r>>6, rl=r&63;
    float s=0.f;
    #pragma unroll
    for (int w2=0;w2<4;++w2) s += sRed[(band*4+w2)*512 + rl*8 + o];
    a.parts[(size_t)ch*65536 + (size_t)(rb*128+r)*8 + o] = s;
  }
}

// ---------------- K3: out2 from parts, fc3, fc4, posterior (32 rows/block) ----
struct K3A {
  const float *parts;
  const float *b2b, *bfc3, *bfc4, *xp, *dy, *innov;
  const u16 *in2T, *wfc3p, *wfc4p;
  float *outPost, *outHSig;
};

__global__ __launch_bounds__(256) void k3(K3A a){
  __shared__ u16 sA[32*168];
  __shared__ u16 sX4[32*168];
  __shared__ float sOut2[32*8];
  const int row0 = blockIdx.x*32;
  const int tid = threadIdx.x;
  {
    int r=tid>>3, o=tid&7, row=row0+r;
    float s = a.b2b[o];
    #pragma unroll
    for (int chv=0;chv<8;++chv) s += a.parts[chv*65536 + row*8 + o];
    sOut2[tid]=s;
    sA[r*168+128+o]=f2b(s);
  }
  for (int i=tid;i<1024;i+=256){
    int r=i>>5, c4=i&31;
    int row = row0 + r, col = c4*4;
    *(s16x4*)(sX4 + r*168 + col) = in2t_load4(a.in2T, row, col);         // hSig
    *(s16x4*)(sA  + r*168 + col) = in2t_load4(a.in2T, row, 128 + col);   // hS_new
  }
  if (tid < 192){ int r=tid/6, c4=tid%6; *(s16x4*)(sA + r*168 + 136 + c4*4) = (s16x4){0,0,0,0}; }
  if (tid < 128){ int r=tid>>2, c4=tid&3; *(s16x4*)(sX4 + r*168 + 144 + c4*4) = (s16x4){0,0,0,0}; }
  __syncthreads();
  if (tid < 128){
    int r = tid>>2, m = tid&3, row = row0+r;
    float g = 1.f/(1.f+__expf(-a.innov[0]));
    float d0 = a.dy[row*2], d1 = a.dy[row*2+1];
    float k0 = sOut2[r*8+m*2], k1 = sOut2[r*8+m*2+1];
    a.outPost[row*4+m] = a.xp[row*4+m] + g*(k0*d0+k1*d1);
  }
  const int w = tid>>6, lane = tid&63, c = lane&15, khi = lane>>4;
  if (w < 2){
    f32x4 C3 = {0,0,0,0};
    #pragma unroll
    for (int kk=0;kk<5;++kk){
      bf16x8 A  = *(const bf16x8*)(sA + (w*16+c)*168 + kk*32 + khi*8);
      bf16x8 Bf = *(const bf16x8*)(a.wfc3p + c*160 + kk*32 + khi*8);
      C3 = mfma16(A,Bf,C3);
    }
    float bj = a.bfc3[c];
    #pragma unroll
    for (int e=0;e<4;++e){
      int r = w*16 + khi*4 + e;
      sX4[r*168 + 128 + c] = f2b(fmaxf(C3[e]+bj, 0.f));
    }
  }
  __syncthreads();
  for (int nn=0;nn<2;++nn){
    int j = (w*2+nn)*16 + c;
    bf16x8 Bf[5];
    #pragma unroll
    for (int kk=0;kk<5;++kk) Bf[kk] = *(const bf16x8*)(a.wfc4p + j*160 + kk*32 + khi*8);
    float bj = a.bfc4[j];
    #pragma unroll
    for (int m=0;m<2;++m){
      f32x4 C = {0,0,0,0};
      #pragma unroll
      for (int kk=0;kk<5;++kk){
        bf16x8 A = *(const bf16x8*)(sX4 + (m*16+c)*168 + kk*32 + khi*8);
        C = mfma16(A, Bf[kk], C);
      }
      #pragma unroll
      for (int e=0;e<4;++e){
        int r = m*16 + khi*4 + e;
        a.outHSig[(row0+r)*128 + j] = fmaxf(C[e]+bj, 0.f);
      }
    }
  }
}

// ---------------- launcher ----------------
extern "C" void kernel_launch(void* const* d_in, const int* in_sizes, int n_in,
                              void* d_out, int out_size, void* d_ws, size_t ws_size,
                              hipStream_t stream){
  const float* y    = (const float*)d_in[0];
  const float* u    = (const float*)d_in[1];
  const float* m1x  = (const float*)d_in[2];
  const float* hQ   = (const float*)d_in[3];
  const float* hSg  = (const float*)d_in[4];
  const float* hS   = (const float*)d_in[5];
  const float* F    = (const float*)d_in[6];
  const float* G    = (const float*)d_in[7];
  const float* Hm   = (const float*)d_in[8];
  const float* innov= (const float*)d_in[9];
  const float* W5   = (const float*)d_in[10];
  const float* b5   = (const float*)d_in[11];
  const float* WihQ = (const float*)d_in[12];
  const float* WhhQ = (const float*)d_in[13];
  const float* bihQ = (const float*)d_in[14];
  const float* bhhQ = (const float*)d_in[15];
  const float* WihSg= (const float*)d_in[16];
  const float* WhhSg= (const float*)d_in[17];
  const float* bihSg= (const float*)d_in[18];
  const float* bhhSg= (const float*)d_in[19];
  const float* W1   = (const float*)d_in[20];
  const float* b1   = (const float*)d_in[21];
  const float* W7   = (const float*)d_in[22];
  const float* b7   = (const float*)d_in[23];
  const float* WihS = (const float*)d_in[24];
  const float* WhhS = (const float*)d_in[25];
  const float* bihS = (const float*)d_in[26];
  const float* bhhS = (const float*)d_in[27];
  const float* W2a  = (const float*)d_in[28];
  const float* b2a  = (const float*)d_in[29];
  const float* W2b  = (const float*)d_in[30];
  const float* b2b  = (const float*)d_in[31];
  const float* W3   = (const float*)d_in[32];
  const float* b3   = (const float*)d_in[33];
  const float* W4   = (const float*)d_in[34];
  const float* b4   = (const float*)d_in[35];

  const size_t WS_NEEDED = 12547072;
  if (ws_size < WS_NEEDED) return;

  char* ws = (char*)d_ws;
  u16*  waB   = (u16*)(ws + 0);
  u16*  wbB   = (u16*)(ws + 5242880);
  u16*  in2T  = (u16*)(ws + 5570560);
  float* parts= (float*)(ws + 9764864);     // 8*65536*4B = 2MB
  float* xp   = (float*)(ws + 11862016);
  float* dyb  = (float*)(ws + 11993088);
  u16* wihQp  = (u16*)(ws + 12058624);
  u16* whhQb  = (u16*)(ws + 12083200);
  u16* wihSgB = (u16*)(ws + 12181504);
  u16* whhSgB = (u16*)(ws + 12279808);
  u16* wihSp  = (u16*)(ws + 12378112);
  u16* whhSb  = (u16*)(ws + 12402688);
  u16* wfc3p  = (u16*)(ws + 12500992);
  u16* wfc4p  = (u16*)(ws + 12506112);

  float* outF    = (float*)d_out;
  float* outPost = outF;
  float* outHQ   = outF + 32768;
  float* outHSig = outF + 32768 + 1048576;
  float* outHS   = outF + 32768 + 2*1048576;

  CVA cv{W2a, W2b, WihQ, WhhQ, WihSg, WhhSg, WihS, WhhS, W3, W4,
         waB, wbB, wihQp, whhQb, wihSgB, whhSgB, wihSp, whhSb, wfc3p, wfc4p};
  kconv<<<dim3(2314), dim3(256), 0, stream>>>(cv);

  K1A a1{y,u,m1x,hQ,hSg,hS,F,G,Hm,W5,b5,bihQ,bhhQ,bihSg,bhhSg,W1,b1,W7,b7,bihS,bhhS,
         wihQp,whhQb,wihSgB,whhSgB,wihSp,whhSb,
         outHQ,outHS,xp,dyb,in2T};
  k1<<<dim3(256), dim3(256), 0, stream>>>(a1);

  K2A a2{waB, wbB, in2T, b2a, parts};
  k2<<<dim3(512), dim3(512), 0, stream>>>(a2);

  K3A a3{parts, b2b, b3, b4, xp, dyb, innov, in2T, wfc3p, wfc4p, outPost, outHSig};
  k3<<<dim3(256), dim3(256), 0, stream>>>(a3);
}